// Round 1
// baseline (697.887 us; speedup 1.0000x reference)
//
#include <hip/hip_runtime.h>

#define DIMD 1536
#define LTOT 2560
#define NS 2048
#define NT 512

typedef __bf16 bf16x8 __attribute__((ext_vector_type(8)));
typedef float f32x4 __attribute__((ext_vector_type(4)));
typedef unsigned short u16;

__device__ __forceinline__ u16 f2bf(float f) {
  union { float f; unsigned u; } v; v.f = f;
  return (u16)((v.u + 0x7fffu + ((v.u >> 16) & 1u)) >> 16);
}

__device__ __forceinline__ void gload_lds16(const void* g, void* l) {
  __builtin_amdgcn_global_load_lds(
      (__attribute__((address_space(1))) void*)(g),
      (__attribute__((address_space(3))) void*)(l), 16, 0, 0);
}

struct CvtArgs {
  const float* src[10];
  u16* dst[10];
  int n[10];
};

__global__ __launch_bounds__(256) void cvt_all(CvtArgs a) {
  const int seg = blockIdx.y;
  const int n = a.n[seg];
  const float* s = a.src[seg];
  u16* d = a.dst[seg];
  const int i = (blockIdx.x * 256 + threadIdx.x) * 4;
  if (i < n) {
    float4 v = *reinterpret_cast<const float4*>(s + i);
    ushort4 o;
    o.x = f2bf(v.x); o.y = f2bf(v.y); o.z = f2bf(v.z); o.w = f2bf(v.w);
    *reinterpret_cast<ushort4*>(d + i) = o;
  }
}

// C(M x 1536) = A(M x 1536) @ W^T + bias; EPI: 0 = +perhead LN -> bf16,
// 1 = bias -> bf16, 2 = bias -> f32
template <int EPI>
__global__ __launch_bounds__(256) void gemm_bt(
    const u16* __restrict__ A, const u16* __restrict__ W,
    const float* __restrict__ bias, const float* __restrict__ gamma,
    void* __restrict__ outp, long out_row_off) {
  __shared__ u16 As[128 * 32];
  __shared__ u16 Bs[128 * 32];
  const int tid = threadIdx.x;
  const int lane = tid & 63;
  const int w = tid >> 6;
  const long m0 = (long)blockIdx.x * 128;
  const int n0 = blockIdx.y * 128;
  const int wr = (w >> 1) * 64, wc = (w & 1) * 64;
  const int l15 = lane & 15, lh = lane >> 4;

  f32x4 acc[4][4] = {};

  const u16* Ab = A + m0 * DIMD;
  const u16* Wb = W + (long)n0 * DIMD;

  for (int k0 = 0; k0 < DIMD; k0 += 32) {
#pragma unroll
    for (int p = 0; p < 2; ++p) {
      const int c = p * 256 + w * 64 + lane;
      const int row = c >> 2, col = (c & 3) * 8;
      gload_lds16(Ab + (long)row * DIMD + k0 + col, As + (p * 256 + w * 64) * 8);
      gload_lds16(Wb + (long)row * DIMD + k0 + col, Bs + (p * 256 + w * 64) * 8);
    }
    __syncthreads();
    bf16x8 af[4], bfr[4];
#pragma unroll
    for (int m = 0; m < 4; ++m)
      af[m] = *reinterpret_cast<const bf16x8*>(As + (wr + m * 16 + l15) * 32 + lh * 8);
#pragma unroll
    for (int n = 0; n < 4; ++n)
      bfr[n] = *reinterpret_cast<const bf16x8*>(Bs + (wc + n * 16 + l15) * 32 + lh * 8);
#pragma unroll
    for (int m = 0; m < 4; ++m)
#pragma unroll
      for (int n = 0; n < 4; ++n)
        acc[m][n] = __builtin_amdgcn_mfma_f32_16x16x32_bf16(af[m], bfr[n], acc[m][n], 0, 0, 0);
    __syncthreads();
  }

  if (EPI == 0) {
    u16* out = (u16*)outp;
#pragma unroll
    for (int m = 0; m < 4; ++m) {
      float val[4][4];
#pragma unroll
      for (int n = 0; n < 4; ++n) {
        const float b = bias[n0 + wc + n * 16 + l15];
#pragma unroll
        for (int r = 0; r < 4; ++r) val[n][r] = acc[m][n][r] + b;
      }
      float s1[4], s2[4];
#pragma unroll
      for (int r = 0; r < 4; ++r) {
        s1[r] = 0.f; s2[r] = 0.f;
#pragma unroll
        for (int n = 0; n < 4; ++n) { s1[r] += val[n][r]; s2[r] += val[n][r] * val[n][r]; }
      }
#pragma unroll
      for (int off = 1; off < 16; off <<= 1) {
#pragma unroll
        for (int r = 0; r < 4; ++r) {
          s1[r] += __shfl_xor(s1[r], off, 16);
          s2[r] += __shfl_xor(s2[r], off, 16);
        }
      }
#pragma unroll
      for (int r = 0; r < 4; ++r) {
        const float mu = s1[r] * (1.0f / 64.0f);
        const float var = s2[r] * (1.0f / 64.0f) - mu * mu;
        const float rstd = rsqrtf(var + 1e-5f);
        const long row = out_row_off + m0 + wr + m * 16 + lh * 4 + r;
#pragma unroll
        for (int n = 0; n < 4; ++n) {
          const float g = gamma[n * 16 + l15];
          out[row * DIMD + n0 + wc + n * 16 + l15] = f2bf((val[n][r] - mu) * rstd * g);
        }
      }
    }
  } else if (EPI == 1) {
    u16* out = (u16*)outp;
#pragma unroll
    for (int m = 0; m < 4; ++m)
#pragma unroll
      for (int r = 0; r < 4; ++r) {
        const long row = out_row_off + m0 + wr + m * 16 + lh * 4 + r;
#pragma unroll
        for (int n = 0; n < 4; ++n)
          out[row * DIMD + n0 + wc + n * 16 + l15] =
              f2bf(acc[m][n][r] + bias[n0 + wc + n * 16 + l15]);
      }
  } else {
    float* out = (float*)outp;
#pragma unroll
    for (int m = 0; m < 4; ++m)
#pragma unroll
      for (int r = 0; r < 4; ++r) {
        const long row = out_row_off + m0 + wr + m * 16 + lh * 4 + r;
#pragma unroll
        for (int n = 0; n < 4; ++n)
          out[row * DIMD + n0 + wc + n * 16 + l15] =
              acc[m][n][r] + bias[n0 + wc + n * 16 + l15];
      }
  }
}

// Flash attention: grid (LTOT/64, 24). Block = 4 waves, wave w handles
// Q rows [bx*64 + w*16, +16), head = blockIdx.y. KV tiles of 32.
__global__ __launch_bounds__(256) void flash_attn(
    const u16* __restrict__ Q, const u16* __restrict__ K,
    const u16* __restrict__ V, u16* __restrict__ O) {
  __shared__ u16 Ks[32 * 64];
  __shared__ u16 Vt[64 * 32];
  __shared__ u16 Ps[4][16 * 32];
  const int tid = threadIdx.x, lane = tid & 63, w = tid >> 6;
  const int l15 = lane & 15, lh = lane >> 4;
  const long hb = (long)blockIdx.y * 64;
  const long q0 = (long)blockIdx.x * 64 + w * 16;

  bf16x8 aq[2];
#pragma unroll
  for (int kh = 0; kh < 2; ++kh)
    aq[kh] = *reinterpret_cast<const bf16x8*>(Q + (q0 + l15) * DIMD + hb + kh * 32 + lh * 8);

  f32x4 oa[4] = {};
  float mrow[4] = {-3e38f, -3e38f, -3e38f, -3e38f};
  float lrow[4] = {0.f, 0.f, 0.f, 0.f};

  for (int kv0 = 0; kv0 < LTOT; kv0 += 32) {
    {
      const int c = w * 64 + lane;
      const int row = c >> 3, col = (c & 7) * 8;
      gload_lds16(K + (long)(kv0 + row) * DIMD + hb + col, Ks + (w * 64) * 8);
      uint4 vv = *reinterpret_cast<const uint4*>(V + (long)(kv0 + row) * DIMD + hb + col);
      const u16* vs = reinterpret_cast<const u16*>(&vv);
#pragma unroll
      for (int i = 0; i < 8; ++i) Vt[(col + i) * 32 + row] = vs[i];
    }
    __syncthreads();

    f32x4 s[2] = {};
#pragma unroll
    for (int c = 0; c < 2; ++c)
#pragma unroll
      for (int kh = 0; kh < 2; ++kh) {
        bf16x8 kb = *reinterpret_cast<const bf16x8*>(Ks + (c * 16 + l15) * 64 + kh * 32 + lh * 8);
        s[c] = __builtin_amdgcn_mfma_f32_16x16x32_bf16(aq[kh], kb, s[c], 0, 0, 0);
      }

    float rm[4], alpha[4], rs[4];
#pragma unroll
    for (int r = 0; r < 4; ++r) {
      s[0][r] *= 0.125f;
      s[1][r] *= 0.125f;
      rm[r] = fmaxf(s[0][r], s[1][r]);
    }
#pragma unroll
    for (int off = 1; off < 16; off <<= 1)
#pragma unroll
      for (int r = 0; r < 4; ++r) rm[r] = fmaxf(rm[r], __shfl_xor(rm[r], off, 16));
#pragma unroll
    for (int r = 0; r < 4; ++r) {
      const float mn = fmaxf(mrow[r], rm[r]);
      alpha[r] = __expf(mrow[r] - mn);
      mrow[r] = mn;
      s[0][r] = __expf(s[0][r] - mn);
      s[1][r] = __expf(s[1][r] - mn);
      rs[r] = s[0][r] + s[1][r];
    }
#pragma unroll
    for (int off = 1; off < 16; off <<= 1)
#pragma unroll
      for (int r = 0; r < 4; ++r) rs[r] += __shfl_xor(rs[r], off, 16);
#pragma unroll
    for (int r = 0; r < 4; ++r) {
      lrow[r] = lrow[r] * alpha[r] + rs[r];
#pragma unroll
      for (int dg = 0; dg < 4; ++dg) oa[dg][r] *= alpha[r];
    }
#pragma unroll
    for (int c = 0; c < 2; ++c)
#pragma unroll
      for (int r = 0; r < 4; ++r)
        Ps[w][(lh * 4 + r) * 32 + c * 16 + l15] = f2bf(s[c][r]);

    bf16x8 pa = *reinterpret_cast<const bf16x8*>(&Ps[w][l15 * 32 + lh * 8]);
#pragma unroll
    for (int dg = 0; dg < 4; ++dg) {
      bf16x8 vb = *reinterpret_cast<const bf16x8*>(Vt + (dg * 16 + l15) * 32 + lh * 8);
      oa[dg] = __builtin_amdgcn_mfma_f32_16x16x32_bf16(pa, vb, oa[dg], 0, 0, 0);
    }
    __syncthreads();
  }

#pragma unroll
  for (int r = 0; r < 4; ++r) {
    const float inv = 1.0f / lrow[r];
    const long row = q0 + lh * 4 + r;
#pragma unroll
    for (int dg = 0; dg < 4; ++dg)
      O[row * DIMD + hb + dg * 16 + l15] = f2bf(oa[dg][r] * inv);
  }
}

extern "C" void kernel_launch(void* const* d_in, const int* in_sizes, int n_in,
                              void* d_out, int out_size, void* d_ws, size_t ws_size,
                              hipStream_t stream) {
  const float* x   = (const float*)d_in[0];
  const float* ex  = (const float*)d_in[1];
  const float* Wq  = (const float*)d_in[2];  const float* bq  = (const float*)d_in[3];
  const float* Wk  = (const float*)d_in[4];  const float* bk  = (const float*)d_in[5];
  const float* Wv  = (const float*)d_in[6];  const float* bv  = (const float*)d_in[7];
  const float* Waq = (const float*)d_in[8];  const float* baq = (const float*)d_in[9];
  const float* Wak = (const float*)d_in[10]; const float* bak = (const float*)d_in[11];
  const float* Wav = (const float*)d_in[12]; const float* bav = (const float*)d_in[13];
  const float* Wo  = (const float*)d_in[14]; const float* bo  = (const float*)d_in[15];
  const float* Wao = (const float*)d_in[16]; const float* bao = (const float*)d_in[17];
  const float* gq  = (const float*)d_in[18]; const float* gk  = (const float*)d_in[19];
  const float* gaq = (const float*)d_in[20]; const float* gak = (const float*)d_in[21];
  float* out = (float*)d_out;

  u16* ws = (u16*)d_ws;
  const size_t WSZ = (size_t)DIMD * DIMD;
  u16* xb   = ws;
  u16* exb  = xb + (size_t)NS * DIMD;
  u16* wb   = exb + (size_t)NT * DIMD;
  u16* qcat = wb + 8 * WSZ;
  u16* kcat = qcat + (size_t)LTOT * DIMD;
  u16* vcat = kcat + (size_t)LTOT * DIMD;
  u16* aout = vcat + (size_t)LTOT * DIMD;

  CvtArgs ca;
  const float* srcs[10] = {x, ex, Wq, Wk, Wv, Waq, Wak, Wav, Wo, Wao};
  u16* dsts[10] = {xb, exb, wb, wb + WSZ, wb + 2 * WSZ, wb + 3 * WSZ,
                   wb + 4 * WSZ, wb + 5 * WSZ, wb + 6 * WSZ, wb + 7 * WSZ};
  const int ns[10] = {NS * DIMD, NT * DIMD, (int)WSZ, (int)WSZ, (int)WSZ,
                      (int)WSZ, (int)WSZ, (int)WSZ, (int)WSZ, (int)WSZ};
  for (int i = 0; i < 10; ++i) { ca.src[i] = srcs[i]; ca.dst[i] = dsts[i]; ca.n[i] = ns[i]; }
  cvt_all<<<dim3((NS * DIMD) / 1024, 10), 256, 0, stream>>>(ca);

  dim3 gs(NS / 128, DIMD / 128);
  dim3 gt(NT / 128, DIMD / 128);
  gemm_bt<0><<<gs, 256, 0, stream>>>(xb,  wb + 0 * WSZ, bq,  gq,  qcat, 0);
  gemm_bt<0><<<gs, 256, 0, stream>>>(xb,  wb + 1 * WSZ, bk,  gk,  kcat, 0);
  gemm_bt<1><<<gs, 256, 0, stream>>>(xb,  wb + 2 * WSZ, bv,  nullptr, vcat, 0);
  gemm_bt<0><<<gt, 256, 0, stream>>>(exb, wb + 3 * WSZ, baq, gaq, qcat, NS);
  gemm_bt<0><<<gt, 256, 0, stream>>>(exb, wb + 4 * WSZ, bak, gak, kcat, NS);
  gemm_bt<1><<<gt, 256, 0, stream>>>(exb, wb + 5 * WSZ, bav, nullptr, vcat, NS);

  flash_attn<<<dim3(LTOT / 64, 24), 256, 0, stream>>>(qcat, kcat, vcat, aout);

  gemm_bt<2><<<gs, 256, 0, stream>>>(aout, wb + 6 * WSZ, bo, nullptr, out, 0);
  gemm_bt<2><<<gt, 256, 0, stream>>>(aout + (size_t)NS * DIMD, wb + 7 * WSZ, bao, nullptr, out, NS);
}

// Round 3
// 417.348 us; speedup vs baseline: 1.6722x; 1.6722x over previous
//
#include <hip/hip_runtime.h>

#define DIMD 1536
#define LTOT 2560
#define NS 2048
#define NT 512

typedef __bf16 bf16x8 __attribute__((ext_vector_type(8)));
typedef float f32x4 __attribute__((ext_vector_type(4)));
typedef unsigned short u16;

__device__ __forceinline__ u16 f2bf(float f) {
  union { float f; unsigned u; } v; v.f = f;
  return (u16)((v.u + 0x7fffu + ((v.u >> 16) & 1u)) >> 16);
}

__device__ __forceinline__ void gload_lds16(const void* g, void* l) {
  __builtin_amdgcn_global_load_lds(
      (__attribute__((address_space(1))) void*)(g),
      (__attribute__((address_space(3))) void*)(l), 16, 0, 0);
}

struct CvtArgs {
  const float* src[10];
  u16* dst[10];
  int n[10];
};

__global__ __launch_bounds__(256) void cvt_all(CvtArgs a) {
  const int seg = blockIdx.y;
  const int n = a.n[seg];
  const float* s = a.src[seg];
  u16* d = a.dst[seg];
  const int i = (blockIdx.x * 256 + threadIdx.x) * 4;
  if (i < n) {
    float4 v = *reinterpret_cast<const float4*>(s + i);
    ushort4 o;
    o.x = f2bf(v.x); o.y = f2bf(v.y); o.z = f2bf(v.z); o.w = f2bf(v.w);
    *reinterpret_cast<ushort4*>(d + i) = o;
  }
}

__device__ __forceinline__ void gemm_mainloop(
    const u16* __restrict__ A, const u16* __restrict__ W,
    u16* As, u16* Bs, f32x4 (&acc)[4][4],
    int w, int lane, int wr, int wc, int l15, int lh) {
  for (int k0 = 0; k0 < DIMD; k0 += 32) {
#pragma unroll
    for (int p = 0; p < 2; ++p) {
      const int c = p * 256 + w * 64 + lane;
      const int row = c >> 2, col = (c & 3) * 8;
      gload_lds16(A + (long)row * DIMD + k0 + col, As + (p * 256 + w * 64) * 8);
      gload_lds16(W + (long)row * DIMD + k0 + col, Bs + (p * 256 + w * 64) * 8);
    }
    __syncthreads();
    bf16x8 af[4], bfr[4];
#pragma unroll
    for (int m = 0; m < 4; ++m)
      af[m] = *reinterpret_cast<const bf16x8*>(As + (wr + m * 16 + l15) * 32 + lh * 8);
#pragma unroll
    for (int n = 0; n < 4; ++n)
      bfr[n] = *reinterpret_cast<const bf16x8*>(Bs + (wc + n * 16 + l15) * 32 + lh * 8);
#pragma unroll
    for (int m = 0; m < 4; ++m)
#pragma unroll
      for (int n = 0; n < 4; ++n)
        acc[m][n] = __builtin_amdgcn_mfma_f32_16x16x32_bf16(af[m], bfr[n], acc[m][n], 0, 0, 0);
    __syncthreads();
  }
}

struct QkvArgs {
  const u16* xb; const u16* exb;
  const u16* w[6];
  const float* b[6];
  const float* g[4];
  u16* qcat; u16* kcat; u16* vcat;
};

// grid (20, 36): bx<16 -> x-side (M=2048), bx>=16 -> encoder (M=512).
// by/12 = sel: 0=Q (LN, scale 1/8), 1=K (LN, swizzled store), 2=V (bias).
__global__ __launch_bounds__(256) void qkv_gemm(QkvArgs a) {
  __shared__ u16 As[128 * 32];
  __shared__ u16 Bs[128 * 32];
  const int tid = threadIdx.x, lane = tid & 63, w = tid >> 6;
  const int l15 = lane & 15, lh = lane >> 4;
  const int side = (blockIdx.x >= 16);
  const int mb = side ? (blockIdx.x - 16) : blockIdx.x;
  const int sel = blockIdx.y / 12;
  const int n0 = (blockIdx.y % 12) * 128;
  const long m0 = (long)mb * 128;
  const long Lbase = side ? NS : 0;
  const int wr = (w >> 1) * 64, wc = (w & 1) * 64;
  const u16* A = (side ? a.exb : a.xb) + m0 * DIMD;
  const u16* W = a.w[side * 3 + sel] + (long)n0 * DIMD;
  const float* bias = a.b[side * 3 + sel];

  f32x4 acc[4][4] = {};
  gemm_mainloop(A, W, As, Bs, acc, w, lane, wr, wc, l15, lh);

  if (sel == 2) {
    u16* out = a.vcat;
#pragma unroll
    for (int m = 0; m < 4; ++m)
#pragma unroll
      for (int r = 0; r < 4; ++r) {
        const long row = Lbase + m0 + wr + m * 16 + lh * 4 + r;
#pragma unroll
        for (int n = 0; n < 4; ++n)
          out[row * DIMD + n0 + wc + n * 16 + l15] =
              f2bf(acc[m][n][r] + bias[n0 + wc + n * 16 + l15]);
      }
  } else {
    const float* gamma = a.g[side * 2 + sel];
    const float gscale = (sel == 0) ? 0.125f : 1.0f;
    u16* out = (sel == 0) ? a.qcat : a.kcat;
    const int swz = (sel == 1);
#pragma unroll
    for (int m = 0; m < 4; ++m) {
      float val[4][4];
#pragma unroll
      for (int n = 0; n < 4; ++n) {
        const float b = bias[n0 + wc + n * 16 + l15];
#pragma unroll
        for (int r = 0; r < 4; ++r) val[n][r] = acc[m][n][r] + b;
      }
      float s1[4], s2[4];
#pragma unroll
      for (int r = 0; r < 4; ++r) {
        s1[r] = 0.f; s2[r] = 0.f;
#pragma unroll
        for (int n = 0; n < 4; ++n) { s1[r] += val[n][r]; s2[r] += val[n][r] * val[n][r]; }
      }
#pragma unroll
      for (int off = 1; off < 16; off <<= 1) {
#pragma unroll
        for (int r = 0; r < 4; ++r) {
          s1[r] += __shfl_xor(s1[r], off, 16);
          s2[r] += __shfl_xor(s2[r], off, 16);
        }
      }
#pragma unroll
      for (int r = 0; r < 4; ++r) {
        const float mu = s1[r] * (1.0f / 64.0f);
        const float var = s2[r] * (1.0f / 64.0f) - mu * mu;
        const float rstd = rsqrtf(var + 1e-5f);
        const long row = Lbase + m0 + wr + m * 16 + lh * 4 + r;
        const int r7s = ((lh * 4 + r) & 7) << 3;
#pragma unroll
        for (int n = 0; n < 4; ++n) {
          const float g = gamma[n * 16 + l15] * gscale;
          const int colg = n0 + wc + n * 16 + l15;
          const int colstore = swz ? ((colg & ~63) | ((colg & 63) ^ r7s)) : colg;
          out[row * DIMD + colstore] = f2bf((val[n][r] - mu) * rstd * g);
        }
      }
    }
  }
}

struct OutArgs {
  const u16* aout;
  const u16* w[2];
  const float* b[2];
  float* out;
};

// grid (20, 12): bx<16 -> img (Wo), bx>=16 -> txt (Wao)
__global__ __launch_bounds__(256) void out_gemm(OutArgs a) {
  __shared__ u16 As[128 * 32];
  __shared__ u16 Bs[128 * 32];
  const int tid = threadIdx.x, lane = tid & 63, w = tid >> 6;
  const int l15 = lane & 15, lh = lane >> 4;
  const int side = (blockIdx.x >= 16);
  const int mb = side ? (blockIdx.x - 16) : blockIdx.x;
  const int n0 = blockIdx.y * 128;
  const long m0 = (long)mb * 128;
  const long Lbase = side ? NS : 0;
  const int wr = (w >> 1) * 64, wc = (w & 1) * 64;
  const u16* A = a.aout + (Lbase + m0) * DIMD;
  const u16* W = a.w[side] + (long)n0 * DIMD;
  const float* bias = a.b[side];

  f32x4 acc[4][4] = {};
  gemm_mainloop(A, W, As, Bs, acc, w, lane, wr, wc, l15, lh);

#pragma unroll
  for (int m = 0; m < 4; ++m)
#pragma unroll
    for (int r = 0; r < 4; ++r) {
      const long row = Lbase + m0 + wr + m * 16 + lh * 4 + r;
#pragma unroll
      for (int n = 0; n < 4; ++n)
        a.out[row * DIMD + n0 + wc + n * 16 + l15] =
            acc[m][n][r] + bias[n0 + wc + n * 16 + l15];
    }
}

// vcat [L][1536] -> VT [24][64][LTOT], store-swizzled: VT[h][d][k ^ ((d&7)<<3)]
__global__ __launch_bounds__(256) void vtrans(const u16* __restrict__ vcat,
                                              u16* __restrict__ VT) {
  const int tid = threadIdx.x;
  const int kv0 = blockIdx.x * 64;
  const int head = blockIdx.y;
  const long hb = (long)head * 64;
#pragma unroll
  for (int p = 0; p < 2; ++p) {
    const int idx = p * 256 + tid;
    const int kl = idx >> 3, db = (idx & 7) * 8;
    uint4 vv = *reinterpret_cast<const uint4*>(vcat + (long)(kv0 + kl) * DIMD + hb + db);
    const u16* vs = reinterpret_cast<const u16*>(&vv);
#pragma unroll
    for (int i = 0; i < 8; ++i) {
      const int d = db + i;
      VT[(hb + d) * LTOT + ((kv0 + kl) ^ ((d & 7) << 3))] = vs[i];
    }
  }
}

// Flash attention. grid (LTOT/64, 24). 4 waves, wave w owns 16 Q rows.
// KV tile 64. K global pre-swizzled per head-row; VT pre-transposed+swizzled.
__global__ __launch_bounds__(256) void flash_attn(
    const u16* __restrict__ Q, const u16* __restrict__ K,
    const u16* __restrict__ VT, u16* __restrict__ O) {
  __shared__ u16 Ks[64 * 64];
  __shared__ u16 Vs[64 * 64];
  __shared__ u16 Ps[4][16 * 64];
  const int tid = threadIdx.x, lane = tid & 63, w = tid >> 6;
  const int l15 = lane & 15, lh = lane >> 4;
  const long hb = (long)blockIdx.y * 64;
  const long q0 = (long)blockIdx.x * 64 + w * 16;
  const int swl = (l15 & 7) << 3;

  bf16x8 aq[2];
#pragma unroll
  for (int kh = 0; kh < 2; ++kh)
    aq[kh] = *reinterpret_cast<const bf16x8*>(Q + (q0 + l15) * DIMD + hb + kh * 32 + lh * 8);

  f32x4 oa[4] = {};
  float mrow[4] = {-3e38f, -3e38f, -3e38f, -3e38f};
  float lrow[4] = {0.f, 0.f, 0.f, 0.f};

  for (int kv0 = 0; kv0 < LTOT; kv0 += 64) {
#pragma unroll
    for (int p = 0; p < 2; ++p) {
      const int idx = p * 256 + tid;
      const int row = idx >> 3, c8 = (idx & 7) * 8;
      gload_lds16(K + (long)(kv0 + row) * DIMD + hb + c8, Ks + (p * 256 + w * 64) * 8);
      gload_lds16(VT + (hb + row) * LTOT + kv0 + c8, Vs + (p * 256 + w * 64) * 8);
    }
    __syncthreads();

    f32x4 s[4] = {};
#pragma unroll
    for (int c = 0; c < 4; ++c)
#pragma unroll
      for (int kh = 0; kh < 2; ++kh) {
        bf16x8 kb = *reinterpret_cast<const bf16x8*>(
            Ks + (c * 16 + l15) * 64 + ((kh * 32 + lh * 8) ^ swl));
        s[c] = __builtin_amdgcn_mfma_f32_16x16x32_bf16(aq[kh], kb, s[c], 0, 0, 0);
      }

    float rm[4], alpha[4], rs[4];
#pragma unroll
    for (int r = 0; r < 4; ++r)
      rm[r] = fmaxf(fmaxf(s[0][r], s[1][r]), fmaxf(s[2][r], s[3][r]));
#pragma unroll
    for (int off = 1; off < 16; off <<= 1)
#pragma unroll
      for (int r = 0; r < 4; ++r) rm[r] = fmaxf(rm[r], __shfl_xor(rm[r], off, 16));
#pragma unroll
    for (int r = 0; r < 4; ++r) {
      const float mn = fmaxf(mrow[r], rm[r]);
      alpha[r] = __expf(mrow[r] - mn);
      mrow[r] = mn;
#pragma unroll
      for (int c = 0; c < 4; ++c) s[c][r] = __expf(s[c][r] - mn);
      rs[r] = (s[0][r] + s[1][r]) + (s[2][r] + s[3][r]);
    }
#pragma unroll
    for (int off = 1; off < 16; off <<= 1)
#pragma unroll
      for (int r = 0; r < 4; ++r) rs[r] += __shfl_xor(rs[r], off, 16);
#pragma unroll
    for (int r = 0; r < 4; ++r) {
      lrow[r] = lrow[r] * alpha[r] + rs[r];
#pragma unroll
      for (int dg = 0; dg < 4; ++dg) oa[dg][r] *= alpha[r];
    }
#pragma unroll
    for (int r = 0; r < 4; ++r) {
      const int prow = lh * 4 + r;
      const int psw = (prow & 7) << 3;
#pragma unroll
      for (int c = 0; c < 4; ++c)
        Ps[w][prow * 64 + ((c * 16 + l15) ^ psw)] = f2bf(s[c][r]);
    }

#pragma unroll
    for (int c2 = 0; c2 < 2; ++c2) {
      bf16x8 pa = *reinterpret_cast<const bf16x8*>(
          &Ps[w][l15 * 64 + ((c2 * 32 + lh * 8) ^ swl)]);
#pragma unroll
      for (int dg = 0; dg < 4; ++dg) {
        bf16x8 vb = *reinterpret_cast<const bf16x8*>(
            Vs + (dg * 16 + l15) * 64 + ((c2 * 32 + lh * 8) ^ swl));
        oa[dg] = __builtin_amdgcn_mfma_f32_16x16x32_bf16(pa, vb, oa[dg], 0, 0, 0);
      }
    }
    __syncthreads();
  }

#pragma unroll
  for (int r = 0; r < 4; ++r) {
    const float inv = 1.0f / lrow[r];
    const long row = q0 + lh * 4 + r;
#pragma unroll
    for (int dg = 0; dg < 4; ++dg)
      O[row * DIMD + hb + dg * 16 + l15] = f2bf(oa[dg][r] * inv);
  }
}

extern "C" void kernel_launch(void* const* d_in, const int* in_sizes, int n_in,
                              void* d_out, int out_size, void* d_ws, size_t ws_size,
                              hipStream_t stream) {
  const float* x   = (const float*)d_in[0];
  const float* ex  = (const float*)d_in[1];
  const float* Wq  = (const float*)d_in[2];  const float* bq  = (const float*)d_in[3];
  const float* Wk  = (const float*)d_in[4];  const float* bk  = (const float*)d_in[5];
  const float* Wv  = (const float*)d_in[6];  const float* bv  = (const float*)d_in[7];
  const float* Waq = (const float*)d_in[8];  const float* baq = (const float*)d_in[9];
  const float* Wak = (const float*)d_in[10]; const float* bak = (const float*)d_in[11];
  const float* Wav = (const float*)d_in[12]; const float* bav = (const float*)d_in[13];
  const float* Wo  = (const float*)d_in[14]; const float* bo  = (const float*)d_in[15];
  const float* Wao = (const float*)d_in[16]; const float* bao = (const float*)d_in[17];
  const float* gq  = (const float*)d_in[18]; const float* gk  = (const float*)d_in[19];
  const float* gaq = (const float*)d_in[20]; const float* gak = (const float*)d_in[21];
  float* out = (float*)d_out;

  u16* ws = (u16*)d_ws;
  const size_t WSZ = (size_t)DIMD * DIMD;
  u16* xb   = ws;
  u16* exb  = xb + (size_t)NS * DIMD;
  u16* wb   = exb + (size_t)NT * DIMD;
  u16* qcat = wb + 8 * WSZ;
  u16* kcat = qcat + (size_t)LTOT * DIMD;
  u16* vcat = kcat + (size_t)LTOT * DIMD;
  u16* VT   = vcat + (size_t)LTOT * DIMD;
  u16* aout = VT + (size_t)LTOT * DIMD;

  CvtArgs ca;
  const float* srcs[10] = {x, ex, Wq, Wk, Wv, Waq, Wak, Wav, Wo, Wao};
  u16* dsts[10] = {xb, exb, wb, wb + WSZ, wb + 2 * WSZ, wb + 3 * WSZ,
                   wb + 4 * WSZ, wb + 5 * WSZ, wb + 6 * WSZ, wb + 7 * WSZ};
  const int ns[10] = {NS * DIMD, NT * DIMD, (int)WSZ, (int)WSZ, (int)WSZ,
                      (int)WSZ, (int)WSZ, (int)WSZ, (int)WSZ, (int)WSZ};
  for (int i = 0; i < 10; ++i) { ca.src[i] = srcs[i]; ca.dst[i] = dsts[i]; ca.n[i] = ns[i]; }
  cvt_all<<<dim3((NS * DIMD) / 1024, 10), 256, 0, stream>>>(ca);

  QkvArgs qa;
  qa.xb = xb; qa.exb = exb;
  qa.w[0] = wb; qa.w[1] = wb + WSZ; qa.w[2] = wb + 2 * WSZ;
  qa.w[3] = wb + 3 * WSZ; qa.w[4] = wb + 4 * WSZ; qa.w[5] = wb + 5 * WSZ;
  qa.b[0] = bq; qa.b[1] = bk; qa.b[2] = bv;
  qa.b[3] = baq; qa.b[4] = bak; qa.b[5] = bav;
  qa.g[0] = gq; qa.g[1] = gk; qa.g[2] = gaq; qa.g[3] = gak;
  qa.qcat = qcat; qa.kcat = kcat; qa.vcat = vcat;
  qkv_gemm<<<dim3(20, 36), 256, 0, stream>>>(qa);

  vtrans<<<dim3(LTOT / 64, 24), 256, 0, stream>>>(vcat, VT);

  flash_attn<<<dim3(LTOT / 64, 24), 256, 0, stream>>>(qcat, kcat, VT, aout);

  OutArgs oa;
  oa.aout = aout;
  oa.w[0] = wb + 6 * WSZ; oa.w[1] = wb + 7 * WSZ;
  oa.b[0] = bo; oa.b[1] = bao;
  oa.out = out;
  out_gemm<<<dim3(20, 12), 256, 0, stream>>>(oa);
}

// Round 4
// 404.711 us; speedup vs baseline: 1.7244x; 1.0312x over previous
//
#include <hip/hip_runtime.h>

#define DIMD 1536
#define LTOT 2560
#define NS 2048
#define NT 512

typedef __bf16 bf16x8 __attribute__((ext_vector_type(8)));
typedef float f32x4 __attribute__((ext_vector_type(4)));
typedef unsigned short u16;

__device__ __forceinline__ u16 f2bf(float f) {
  union { float f; unsigned u; } v; v.f = f;
  return (u16)((v.u + 0x7fffu + ((v.u >> 16) & 1u)) >> 16);
}

__device__ __forceinline__ void gload_lds16(const void* g, void* l) {
  __builtin_amdgcn_global_load_lds(
      (__attribute__((address_space(1))) void*)(g),
      (__attribute__((address_space(3))) void*)(l), 16, 0, 0);
}

struct CvtArgs {
  const float* src[10];
  u16* dst[10];
  int n[10];
};

__global__ __launch_bounds__(256) void cvt_all(CvtArgs a) {
  const int seg = blockIdx.y;
  const int n = a.n[seg];
  const float* s = a.src[seg];
  u16* d = a.dst[seg];
  const int i = (blockIdx.x * 256 + threadIdx.x) * 4;
  if (i < n) {
    float4 v = *reinterpret_cast<const float4*>(s + i);
    ushort4 o;
    o.x = f2bf(v.x); o.y = f2bf(v.y); o.z = f2bf(v.z); o.w = f2bf(v.w);
    *reinterpret_cast<ushort4*>(d + i) = o;
  }
}

// BK=64 mainloop with T2 XOR swizzle (both-sides: inverse-swizzled global
// source feeding linear gload_lds dest, swizzled ds_read).
__device__ __forceinline__ void gemm_mainloop(
    const u16* __restrict__ A, const u16* __restrict__ W,
    u16* As, u16* Bs, f32x4 (&acc)[4][4],
    int w, int lane, int wr, int wc, int l15, int lh) {
  const int swk = (l15 & 7) << 3;
  for (int k0 = 0; k0 < DIMD; k0 += 64) {
#pragma unroll
    for (int ph = 0; ph < 4; ++ph) {
      const int idx = ph * 256 + w * 64 + lane;
      const int row = idx >> 3;
      const int scol = ((idx & 7) ^ (row & 7)) * 8;
      gload_lds16(A + (long)row * DIMD + k0 + scol, As + (ph * 256 + w * 64) * 8);
      gload_lds16(W + (long)row * DIMD + k0 + scol, Bs + (ph * 256 + w * 64) * 8);
    }
    __syncthreads();
#pragma unroll
    for (int kk = 0; kk < 2; ++kk) {
      const int kc = (kk * 32 + lh * 8) ^ swk;
      bf16x8 af[4], bfr[4];
#pragma unroll
      for (int m = 0; m < 4; ++m)
        af[m] = *reinterpret_cast<const bf16x8*>(As + (wr + m * 16 + l15) * 64 + kc);
#pragma unroll
      for (int n = 0; n < 4; ++n)
        bfr[n] = *reinterpret_cast<const bf16x8*>(Bs + (wc + n * 16 + l15) * 64 + kc);
#pragma unroll
      for (int m = 0; m < 4; ++m)
#pragma unroll
        for (int n = 0; n < 4; ++n)
          acc[m][n] = __builtin_amdgcn_mfma_f32_16x16x32_bf16(af[m], bfr[n], acc[m][n], 0, 0, 0);
    }
    __syncthreads();
  }
}

struct QkvArgs {
  const u16* xb; const u16* exb;
  const u16* w[6];
  const float* b[6];
  const float* g[4];
  u16* qcat; u16* kcat; u16* vcat;
};

// grid (20, 36): bx<16 -> x-side (M=2048), bx>=16 -> encoder (M=512).
// by/12 = sel: 0=Q (LN, scale log2e/8 folded), 1=K (LN, swizzled store), 2=V.
__global__ __launch_bounds__(256) void qkv_gemm(QkvArgs a) {
  __shared__ u16 As[128 * 64];
  __shared__ u16 Bs[128 * 64];
  const int tid = threadIdx.x, lane = tid & 63, w = tid >> 6;
  const int l15 = lane & 15, lh = lane >> 4;
  const int side = (blockIdx.x >= 16);
  const int mb = side ? (blockIdx.x - 16) : blockIdx.x;
  const int sel = blockIdx.y / 12;
  const int n0 = (blockIdx.y % 12) * 128;
  const long m0 = (long)mb * 128;
  const long Lbase = side ? NS : 0;
  const int wr = (w >> 1) * 64, wc = (w & 1) * 64;
  const u16* A = (side ? a.exb : a.xb) + m0 * DIMD;
  const u16* W = a.w[side * 3 + sel] + (long)n0 * DIMD;
  const float* bias = a.b[side * 3 + sel];

  f32x4 acc[4][4] = {};
  gemm_mainloop(A, W, As, Bs, acc, w, lane, wr, wc, l15, lh);

  if (sel == 2) {
    u16* out = a.vcat;
#pragma unroll
    for (int m = 0; m < 4; ++m)
#pragma unroll
      for (int r = 0; r < 4; ++r) {
        const long row = Lbase + m0 + wr + m * 16 + lh * 4 + r;
#pragma unroll
        for (int n = 0; n < 4; ++n)
          out[row * DIMD + n0 + wc + n * 16 + l15] =
              f2bf(acc[m][n][r] + bias[n0 + wc + n * 16 + l15]);
      }
  } else {
    const float* gamma = a.g[side * 2 + sel];
    // Q: fold softmax scale 1/8 AND log2(e) so attention uses bare exp2.
    const float gscale = (sel == 0) ? 0.125f * 1.4426950408889634f : 1.0f;
    u16* out = (sel == 0) ? a.qcat : a.kcat;
    const int swz = (sel == 1);
#pragma unroll
    for (int m = 0; m < 4; ++m) {
      float val[4][4];
#pragma unroll
      for (int n = 0; n < 4; ++n) {
        const float b = bias[n0 + wc + n * 16 + l15];
#pragma unroll
        for (int r = 0; r < 4; ++r) val[n][r] = acc[m][n][r] + b;
      }
      float s1[4], s2[4];
#pragma unroll
      for (int r = 0; r < 4; ++r) {
        s1[r] = 0.f; s2[r] = 0.f;
#pragma unroll
        for (int n = 0; n < 4; ++n) { s1[r] += val[n][r]; s2[r] += val[n][r] * val[n][r]; }
      }
#pragma unroll
      for (int off = 1; off < 16; off <<= 1) {
#pragma unroll
        for (int r = 0; r < 4; ++r) {
          s1[r] += __shfl_xor(s1[r], off, 16);
          s2[r] += __shfl_xor(s2[r], off, 16);
        }
      }
#pragma unroll
      for (int r = 0; r < 4; ++r) {
        const float mu = s1[r] * (1.0f / 64.0f);
        const float var = s2[r] * (1.0f / 64.0f) - mu * mu;
        const float rstd = rsqrtf(var + 1e-5f);
        const long row = Lbase + m0 + wr + m * 16 + lh * 4 + r;
        const int r7s = ((lh * 4 + r) & 7) << 3;
#pragma unroll
        for (int n = 0; n < 4; ++n) {
          const float g = gamma[n * 16 + l15] * gscale;
          const int colg = n0 + wc + n * 16 + l15;
          const int colstore = swz ? ((colg & ~63) | ((colg & 63) ^ r7s)) : colg;
          out[row * DIMD + colstore] = f2bf((val[n][r] - mu) * rstd * g);
        }
      }
    }
  }
}

struct OutArgs {
  const u16* aout;
  const u16* w[2];
  const float* b[2];
  float* out;
};

// grid (20, 12): bx<16 -> img (Wo), bx>=16 -> txt (Wao)
__global__ __launch_bounds__(256) void out_gemm(OutArgs a) {
  __shared__ u16 As[128 * 64];
  __shared__ u16 Bs[128 * 64];
  const int tid = threadIdx.x, lane = tid & 63, w = tid >> 6;
  const int l15 = lane & 15, lh = lane >> 4;
  const int side = (blockIdx.x >= 16);
  const int mb = side ? (blockIdx.x - 16) : blockIdx.x;
  const int n0 = blockIdx.y * 128;
  const long m0 = (long)mb * 128;
  const long Lbase = side ? NS : 0;
  const int wr = (w >> 1) * 64, wc = (w & 1) * 64;
  const u16* A = a.aout + (Lbase + m0) * DIMD;
  const u16* W = a.w[side] + (long)n0 * DIMD;
  const float* bias = a.b[side];

  f32x4 acc[4][4] = {};
  gemm_mainloop(A, W, As, Bs, acc, w, lane, wr, wc, l15, lh);

#pragma unroll
  for (int m = 0; m < 4; ++m)
#pragma unroll
    for (int r = 0; r < 4; ++r) {
      const long row = Lbase + m0 + wr + m * 16 + lh * 4 + r;
#pragma unroll
      for (int n = 0; n < 4; ++n)
        a.out[row * DIMD + n0 + wc + n * 16 + l15] =
            acc[m][n][r] + bias[n0 + wc + n * 16 + l15];
    }
}

// vcat [L][1536] -> VT [24][64][LTOT], store-swizzled: VT[h][d][k ^ ((d&7)<<3)]
__global__ __launch_bounds__(256) void vtrans(const u16* __restrict__ vcat,
                                              u16* __restrict__ VT) {
  const int tid = threadIdx.x;
  const int kv0 = blockIdx.x * 64;
  const int head = blockIdx.y;
  const long hb = (long)head * 64;
#pragma unroll
  for (int p = 0; p < 2; ++p) {
    const int idx = p * 256 + tid;
    const int kl = idx >> 3, db = (idx & 7) * 8;
    uint4 vv = *reinterpret_cast<const uint4*>(vcat + (long)(kv0 + kl) * DIMD + hb + db);
    const u16* vs = reinterpret_cast<const u16*>(&vv);
#pragma unroll
    for (int i = 0; i < 8; ++i) {
      const int d = db + i;
      VT[(hb + d) * LTOT + ((kv0 + kl) ^ ((d & 7) << 3))] = vs[i];
    }
  }
}

// Flash attention, max-free softmax (|s| <= 8*log2e guaranteed by LN norms).
// grid (LTOT/64, 24). 4 waves; wave w owns 16 Q rows. KV tile 128.
__global__ __launch_bounds__(256) void flash_attn(
    const u16* __restrict__ Q, const u16* __restrict__ K,
    const u16* __restrict__ VT, u16* __restrict__ O) {
  __shared__ u16 Ks[128 * 64];
  __shared__ u16 Vs[64 * 128];
  __shared__ u16 Ps[4][16 * 128];
  const int tid = threadIdx.x, lane = tid & 63, w = tid >> 6;
  const int l15 = lane & 15, lh = lane >> 4;
  const long hb = (long)blockIdx.y * 64;
  const long q0 = (long)blockIdx.x * 64 + w * 16;
  const int swl = (l15 & 7) << 3;

  bf16x8 aq[2];
#pragma unroll
  for (int kh = 0; kh < 2; ++kh)
    aq[kh] = *reinterpret_cast<const bf16x8*>(Q + (q0 + l15) * DIMD + hb + kh * 32 + lh * 8);

  f32x4 oa[4] = {};
  float lrow[4] = {0.f, 0.f, 0.f, 0.f};

  for (int kv0 = 0; kv0 < LTOT; kv0 += 128) {
#pragma unroll
    for (int ph = 0; ph < 4; ++ph) {
      const int idx = ph * 256 + tid;
      const int rowk = idx >> 3, ck = (idx & 7) * 8;
      gload_lds16(K + (long)(kv0 + rowk) * DIMD + hb + ck, Ks + (ph * 256 + w * 64) * 8);
      const int rowv = idx >> 4, cv = (idx & 15) * 8;
      gload_lds16(VT + (hb + rowv) * LTOT + kv0 + cv, Vs + (ph * 256 + w * 64) * 8);
    }
    __syncthreads();

    f32x4 s[8] = {};
#pragma unroll
    for (int c = 0; c < 8; ++c)
#pragma unroll
      for (int kh = 0; kh < 2; ++kh) {
        bf16x8 kb = *reinterpret_cast<const bf16x8*>(
            Ks + (c * 16 + l15) * 64 + ((kh * 32 + lh * 8) ^ swl));
        s[c] = __builtin_amdgcn_mfma_f32_16x16x32_bf16(aq[kh], kb, s[c], 0, 0, 0);
      }

#pragma unroll
    for (int r = 0; r < 4; ++r) {
      const int prow = lh * 4 + r;
      const int psw = (prow & 7) << 3;
      float acc = 0.f;
#pragma unroll
      for (int c = 0; c < 8; ++c) {
        const float p = exp2f(s[c][r]);
        acc += p;
        Ps[w][prow * 128 + ((c * 16 + l15) ^ psw)] = f2bf(p);
      }
      lrow[r] += acc;
    }

#pragma unroll
    for (int c2 = 0; c2 < 4; ++c2) {
      bf16x8 pa = *reinterpret_cast<const bf16x8*>(
          &Ps[w][l15 * 128 + ((c2 * 32 + lh * 8) ^ swl)]);
#pragma unroll
      for (int dg = 0; dg < 4; ++dg) {
        bf16x8 vb = *reinterpret_cast<const bf16x8*>(
            Vs + (dg * 16 + l15) * 128 + ((c2 * 32 + lh * 8) ^ swl));
        oa[dg] = __builtin_amdgcn_mfma_f32_16x16x32_bf16(pa, vb, oa[dg], 0, 0, 0);
      }
    }
    __syncthreads();
  }

#pragma unroll
  for (int off = 1; off < 16; off <<= 1)
#pragma unroll
    for (int r = 0; r < 4; ++r) lrow[r] += __shfl_xor(lrow[r], off, 16);

#pragma unroll
  for (int r = 0; r < 4; ++r) {
    const float inv = 1.0f / lrow[r];
    const long row = q0 + lh * 4 + r;
#pragma unroll
    for (int dg = 0; dg < 4; ++dg)
      O[row * DIMD + hb + dg * 16 + l15] = f2bf(oa[dg][r] * inv);
  }
}

extern "C" void kernel_launch(void* const* d_in, const int* in_sizes, int n_in,
                              void* d_out, int out_size, void* d_ws, size_t ws_size,
                              hipStream_t stream) {
  const float* x   = (const float*)d_in[0];
  const float* ex  = (const float*)d_in[1];
  const float* Wq  = (const float*)d_in[2];  const float* bq  = (const float*)d_in[3];
  const float* Wk  = (const float*)d_in[4];  const float* bk  = (const float*)d_in[5];
  const float* Wv  = (const float*)d_in[6];  const float* bv  = (const float*)d_in[7];
  const float* Waq = (const float*)d_in[8];  const float* baq = (const float*)d_in[9];
  const float* Wak = (const float*)d_in[10]; const float* bak = (const float*)d_in[11];
  const float* Wav = (const float*)d_in[12]; const float* bav = (const float*)d_in[13];
  const float* Wo  = (const float*)d_in[14]; const float* bo  = (const float*)d_in[15];
  const float* Wao = (const float*)d_in[16]; const float* bao = (const float*)d_in[17];
  const float* gq  = (const float*)d_in[18]; const float* gk  = (const float*)d_in[19];
  const float* gaq = (const float*)d_in[20]; const float* gak = (const float*)d_in[21];
  float* out = (float*)d_out;

  u16* ws = (u16*)d_ws;
  const size_t WSZ = (size_t)DIMD * DIMD;
  u16* xb   = ws;
  u16* exb  = xb + (size_t)NS * DIMD;
  u16* wb   = exb + (size_t)NT * DIMD;
  u16* qcat = wb + 8 * WSZ;
  u16* kcat = qcat + (size_t)LTOT * DIMD;
  u16* vcat = kcat + (size_t)LTOT * DIMD;
  u16* VT   = vcat + (size_t)LTOT * DIMD;
  u16* aout = VT + (size_t)LTOT * DIMD;

  CvtArgs ca;
  const float* srcs[10] = {x, ex, Wq, Wk, Wv, Waq, Wak, Wav, Wo, Wao};
  u16* dsts[10] = {xb, exb, wb, wb + WSZ, wb + 2 * WSZ, wb + 3 * WSZ,
                   wb + 4 * WSZ, wb + 5 * WSZ, wb + 6 * WSZ, wb + 7 * WSZ};
  const int ns[10] = {NS * DIMD, NT * DIMD, (int)WSZ, (int)WSZ, (int)WSZ,
                      (int)WSZ, (int)WSZ, (int)WSZ, (int)WSZ, (int)WSZ};
  for (int i = 0; i < 10; ++i) { ca.src[i] = srcs[i]; ca.dst[i] = dsts[i]; ca.n[i] = ns[i]; }
  cvt_all<<<dim3((NS * DIMD) / 1024, 10), 256, 0, stream>>>(ca);

  QkvArgs qa;
  qa.xb = xb; qa.exb = exb;
  qa.w[0] = wb; qa.w[1] = wb + WSZ; qa.w[2] = wb + 2 * WSZ;
  qa.w[3] = wb + 3 * WSZ; qa.w[4] = wb + 4 * WSZ; qa.w[5] = wb + 5 * WSZ;
  qa.b[0] = bq; qa.b[1] = bk; qa.b[2] = bv;
  qa.b[3] = baq; qa.b[4] = bak; qa.b[5] = bav;
  qa.g[0] = gq; qa.g[1] = gk; qa.g[2] = gaq; qa.g[3] = gak;
  qa.qcat = qcat; qa.kcat = kcat; qa.vcat = vcat;
  qkv_gemm<<<dim3(20, 36), 256, 0, stream>>>(qa);

  vtrans<<<dim3(LTOT / 64, 24), 256, 0, stream>>>(vcat, VT);

  flash_attn<<<dim3(LTOT / 64, 24), 256, 0, stream>>>(qcat, kcat, VT, aout);

  OutArgs oa;
  oa.aout = aout;
  oa.w[0] = wb + 6 * WSZ; oa.w[1] = wb + 7 * WSZ;
  oa.b[0] = bo; oa.b[1] = bao;
  oa.out = out;
  out_gemm<<<dim3(20, 12), 256, 0, stream>>>(oa);
}

// Round 5
// 368.528 us; speedup vs baseline: 1.8937x; 1.0982x over previous
//
#include <hip/hip_runtime.h>

#define DIMD 1536
#define LTOT 2560
#define NS 2048
#define NT 512

typedef __bf16 bf16x8 __attribute__((ext_vector_type(8)));
typedef float f32x4 __attribute__((ext_vector_type(4)));
typedef int i32x2 __attribute__((ext_vector_type(2)));
typedef unsigned short u16;
typedef unsigned int u32;

__device__ __forceinline__ u16 f2bf(float f) {
  union { float f; unsigned u; } v; v.f = f;
  return (u16)((v.u + 0x7fffu + ((v.u >> 16) & 1u)) >> 16);
}

__device__ __forceinline__ u32 cvt_pk_bf16(float a, float b) {
  u32 r;
  asm("v_cvt_pk_bf16_f32 %0, %1, %2" : "=v"(r) : "v"(a), "v"(b));
  return r;
}

__device__ __forceinline__ void gload_lds16(const void* g, void* l) {
  __builtin_amdgcn_global_load_lds(
      (__attribute__((address_space(1))) void*)(g),
      (__attribute__((address_space(3))) void*)(l), 16, 0, 0);
}

struct CvtArgs {
  const float* src[10];
  u16* dst[10];
  int n[10];
};

__global__ __launch_bounds__(256) void cvt_all(CvtArgs a) {
  const int seg = blockIdx.y;
  const int n = a.n[seg];
  const float* s = a.src[seg];
  u16* d = a.dst[seg];
  const int i = (blockIdx.x * 256 + threadIdx.x) * 4;
  if (i < n) {
    float4 v = *reinterpret_cast<const float4*>(s + i);
    ushort4 o;
    o.x = f2bf(v.x); o.y = f2bf(v.y); o.z = f2bf(v.z); o.w = f2bf(v.w);
    *reinterpret_cast<ushort4*>(d + i) = o;
  }
}

// BK=32 mainloop (round-3 measured-good version).
__device__ __forceinline__ void gemm_mainloop(
    const u16* __restrict__ A, const u16* __restrict__ W,
    u16* As, u16* Bs, f32x4 (&acc)[4][4],
    int w, int lane, int wr, int wc, int l15, int lh) {
  for (int k0 = 0; k0 < DIMD; k0 += 32) {
#pragma unroll
    for (int p = 0; p < 2; ++p) {
      const int c = p * 256 + w * 64 + lane;
      const int row = c >> 2, col = (c & 3) * 8;
      gload_lds16(A + (long)row * DIMD + k0 + col, As + (p * 256 + w * 64) * 8);
      gload_lds16(W + (long)row * DIMD + k0 + col, Bs + (p * 256 + w * 64) * 8);
    }
    __syncthreads();
    bf16x8 af[4], bfr[4];
#pragma unroll
    for (int m = 0; m < 4; ++m)
      af[m] = *reinterpret_cast<const bf16x8*>(As + (wr + m * 16 + l15) * 32 + lh * 8);
#pragma unroll
    for (int n = 0; n < 4; ++n)
      bfr[n] = *reinterpret_cast<const bf16x8*>(Bs + (wc + n * 16 + l15) * 32 + lh * 8);
#pragma unroll
    for (int m = 0; m < 4; ++m)
#pragma unroll
      for (int n = 0; n < 4; ++n)
        acc[m][n] = __builtin_amdgcn_mfma_f32_16x16x32_bf16(af[m], bfr[n], acc[m][n], 0, 0, 0);
    __syncthreads();
  }
}

struct QkvArgs {
  const u16* xb; const u16* exb;
  const u16* w[6];
  const float* b[6];
  const float* g[4];
  u16* qcat; u16* kcat; u16* vcat;
};

// grid (20, 36): bx<16 -> x-side (M=2048), bx>=16 -> encoder (M=512).
// by/12 = sel: 0=Q (LN, scale log2e/8 folded), 1=K (LN, swizzled store), 2=V.
__global__ __launch_bounds__(256) void qkv_gemm(QkvArgs a) {
  __shared__ u16 As[128 * 32];
  __shared__ u16 Bs[128 * 32];
  const int tid = threadIdx.x, lane = tid & 63, w = tid >> 6;
  const int l15 = lane & 15, lh = lane >> 4;
  const int side = (blockIdx.x >= 16);
  const int mb = side ? (blockIdx.x - 16) : blockIdx.x;
  const int sel = blockIdx.y / 12;
  const int n0 = (blockIdx.y % 12) * 128;
  const long m0 = (long)mb * 128;
  const long Lbase = side ? NS : 0;
  const int wr = (w >> 1) * 64, wc = (w & 1) * 64;
  const u16* A = (side ? a.exb : a.xb) + m0 * DIMD;
  const u16* W = a.w[side * 3 + sel] + (long)n0 * DIMD;
  const float* bias = a.b[side * 3 + sel];

  f32x4 acc[4][4] = {};
  gemm_mainloop(A, W, As, Bs, acc, w, lane, wr, wc, l15, lh);

  if (sel == 2) {
    u16* out = a.vcat;
#pragma unroll
    for (int m = 0; m < 4; ++m)
#pragma unroll
      for (int r = 0; r < 4; ++r) {
        const long row = Lbase + m0 + wr + m * 16 + lh * 4 + r;
#pragma unroll
        for (int n = 0; n < 4; ++n)
          out[row * DIMD + n0 + wc + n * 16 + l15] =
              f2bf(acc[m][n][r] + bias[n0 + wc + n * 16 + l15]);
      }
  } else {
    const float* gamma = a.g[side * 2 + sel];
    // Q: fold softmax scale 1/8 AND log2(e) so attention uses bare exp2.
    const float gscale = (sel == 0) ? 0.125f * 1.4426950408889634f : 1.0f;
    u16* out = (sel == 0) ? a.qcat : a.kcat;
    const int swz = (sel == 1);
#pragma unroll
    for (int m = 0; m < 4; ++m) {
      float val[4][4];
#pragma unroll
      for (int n = 0; n < 4; ++n) {
        const float b = bias[n0 + wc + n * 16 + l15];
#pragma unroll
        for (int r = 0; r < 4; ++r) val[n][r] = acc[m][n][r] + b;
      }
      float s1[4], s2[4];
#pragma unroll
      for (int r = 0; r < 4; ++r) {
        s1[r] = 0.f; s2[r] = 0.f;
#pragma unroll
        for (int n = 0; n < 4; ++n) { s1[r] += val[n][r]; s2[r] += val[n][r] * val[n][r]; }
      }
#pragma unroll
      for (int off = 1; off < 16; off <<= 1) {
#pragma unroll
        for (int r = 0; r < 4; ++r) {
          s1[r] += __shfl_xor(s1[r], off, 16);
          s2[r] += __shfl_xor(s2[r], off, 16);
        }
      }
#pragma unroll
      for (int r = 0; r < 4; ++r) {
        const float mu = s1[r] * (1.0f / 64.0f);
        const float var = s2[r] * (1.0f / 64.0f) - mu * mu;
        const float rstd = rsqrtf(var + 1e-5f);
        const long row = Lbase + m0 + wr + m * 16 + lh * 4 + r;
        const int r7s = ((lh * 4 + r) & 7) << 3;
#pragma unroll
        for (int n = 0; n < 4; ++n) {
          const float g = gamma[n * 16 + l15] * gscale;
          const int colg = n0 + wc + n * 16 + l15;
          const int colstore = swz ? ((colg & ~63) | ((colg & 63) ^ r7s)) : colg;
          out[row * DIMD + colstore] = f2bf((val[n][r] - mu) * rstd * g);
        }
      }
    }
  }
}

struct OutArgs {
  const u16* aout;
  const u16* w[2];
  const float* b[2];
  float* out;
};

// grid (20, 12): bx<16 -> img (Wo), bx>=16 -> txt (Wao)
__global__ __launch_bounds__(256) void out_gemm(OutArgs a) {
  __shared__ u16 As[128 * 32];
  __shared__ u16 Bs[128 * 32];
  const int tid = threadIdx.x, lane = tid & 63, w = tid >> 6;
  const int l15 = lane & 15, lh = lane >> 4;
  const int side = (blockIdx.x >= 16);
  const int mb = side ? (blockIdx.x - 16) : blockIdx.x;
  const int n0 = blockIdx.y * 128;
  const long m0 = (long)mb * 128;
  const long Lbase = side ? NS : 0;
  const int wr = (w >> 1) * 64, wc = (w & 1) * 64;
  const u16* A = a.aout + (Lbase + m0) * DIMD;
  const u16* W = a.w[side] + (long)n0 * DIMD;
  const float* bias = a.b[side];

  f32x4 acc[4][4] = {};
  gemm_mainloop(A, W, As, Bs, acc, w, lane, wr, wc, l15, lh);

#pragma unroll
  for (int m = 0; m < 4; ++m)
#pragma unroll
    for (int r = 0; r < 4; ++r) {
      const long row = Lbase + m0 + wr + m * 16 + lh * 4 + r;
#pragma unroll
      for (int n = 0; n < 4; ++n)
        a.out[row * DIMD + n0 + wc + n * 16 + l15] =
            acc[m][n][r] + bias[n0 + wc + n * 16 + l15];
    }
}

// vcat [L][1536] -> VT [24][64][LTOT], store-swizzled: VT[h][d][k ^ ((d&7)<<3)]
__global__ __launch_bounds__(256) void vtrans(const u16* __restrict__ vcat,
                                              u16* __restrict__ VT) {
  const int tid = threadIdx.x;
  const int kv0 = blockIdx.x * 64;
  const int head = blockIdx.y;
  const long hb = (long)head * 64;
#pragma unroll
  for (int p = 0; p < 2; ++p) {
    const int idx = p * 256 + tid;
    const int kl = idx >> 3, db = (idx & 7) * 8;
    uint4 vv = *reinterpret_cast<const uint4*>(vcat + (long)(kv0 + kl) * DIMD + hb + db);
    const u16* vs = reinterpret_cast<const u16*>(&vv);
#pragma unroll
    for (int i = 0; i < 8; ++i) {
      const int d = db + i;
      VT[(hb + d) * LTOT + ((kv0 + kl) ^ ((d & 7) << 3))] = vs[i];
    }
  }
}

// Flash attention, max-free softmax, swapped QK^T (S^T = mfma(K,Q)) with
// fully in-register P->A-fragment construction (cvt_pk + permlane32_swap +
// shfl_xor(16)). No P LDS buffer. grid (LTOT/64, 24), 4 waves, KV tile 128.
__global__ __launch_bounds__(256) void flash_attn(
    const u16* __restrict__ Q, const u16* __restrict__ K,
    const u16* __restrict__ VT, u16* __restrict__ O) {
  __shared__ u16 Ks[128 * 64];
  __shared__ u16 Vs[64 * 128];
  const int tid = threadIdx.x, lane = tid & 63, w = tid >> 6;
  const int l15 = lane & 15, lh = lane >> 4;
  const bool bsel = lh & 1;
  const long hb = (long)blockIdx.y * 64;
  const long q0 = (long)blockIdx.x * 64 + w * 16;
  const int swl = (l15 & 7) << 3;

  bf16x8 aq[2];
#pragma unroll
  for (int kh = 0; kh < 2; ++kh)
    aq[kh] = *reinterpret_cast<const bf16x8*>(Q + (q0 + l15) * DIMD + hb + kh * 32 + lh * 8);

  f32x4 oa[4] = {};
  float lsum = 0.f;

  for (int kv0 = 0; kv0 < LTOT; kv0 += 128) {
#pragma unroll
    for (int ph = 0; ph < 4; ++ph) {
      const int idx = ph * 256 + tid;
      const int rowk = idx >> 3, ck = (idx & 7) * 8;
      gload_lds16(K + (long)(kv0 + rowk) * DIMD + hb + ck, Ks + (ph * 256 + w * 64) * 8);
      const int rowv = idx >> 4, cv = (idx & 15) * 8;
      gload_lds16(VT + (hb + rowv) * LTOT + kv0 + cv, Vs + (ph * 256 + w * 64) * 8);
    }
    __syncthreads();

    // S^T tile: s[c][r] = S[k = 16c + 4lh + r][q = l15]
    f32x4 s[8] = {};
#pragma unroll
    for (int c = 0; c < 8; ++c)
#pragma unroll
      for (int kh = 0; kh < 2; ++kh) {
        bf16x8 kb = *reinterpret_cast<const bf16x8*>(
            Ks + (c * 16 + l15) * 64 + ((kh * 32 + lh * 8) ^ swl));
        s[c] = __builtin_amdgcn_mfma_f32_16x16x32_bf16(kb, aq[kh], s[c], 0, 0, 0);
      }

    // exp2 (scale+log2e folded into Q gamma) + lane-local partial row sum.
    u32 lo[8], hi[8];
#pragma unroll
    for (int c = 0; c < 8; ++c) {
      float p0 = exp2f(s[c][0]), p1 = exp2f(s[c][1]);
      float p2 = exp2f(s[c][2]), p3 = exp2f(s[c][3]);
      lsum += (p0 + p1) + (p2 + p3);
      lo[c] = cvt_pk_bf16(p0, p1);
      hi[c] = cvt_pk_bf16(p2, p3);
    }

    // Build P A-fragments in-register and run PV.
#pragma unroll
    for (int ks = 0; ks < 4; ++ks) {
      i32x2 L = __builtin_amdgcn_permlane32_swap((int)lo[2 * ks], (int)lo[2 * ks + 1], false, false);
      i32x2 H = __builtin_amdgcn_permlane32_swap((int)hi[2 * ks], (int)hi[2 * ks + 1], false, false);
      const int sLy = __shfl_xor(L.y, 16);
      const int sHy = __shfl_xor(H.y, 16);
      const int sLx = __shfl_xor(L.x, 16);
      const int sHx = __shfl_xor(H.x, 16);
      union { int w4[4]; bf16x8 v; } pu;
      pu.w4[0] = bsel ? sLy : L.x;
      pu.w4[1] = bsel ? sHy : H.x;
      pu.w4[2] = bsel ? L.y : sLx;
      pu.w4[3] = bsel ? H.y : sHx;
#pragma unroll
      for (int dg = 0; dg < 4; ++dg) {
        bf16x8 vb = *reinterpret_cast<const bf16x8*>(
            Vs + (dg * 16 + l15) * 128 + ((ks * 32 + lh * 8) ^ swl));
        oa[dg] = __builtin_amdgcn_mfma_f32_16x16x32_bf16(pu.v, vb, oa[dg], 0, 0, 0);
      }
    }
    __syncthreads();
  }

  // lsum currently: partial sum for q = l15. Total it, then fetch per-output-row.
  lsum += __shfl_xor(lsum, 16);
  lsum += __shfl_xor(lsum, 32);

#pragma unroll
  for (int r = 0; r < 4; ++r) {
    const float inv = 1.0f / __shfl(lsum, lh * 4 + r);
    const long row = q0 + lh * 4 + r;
#pragma unroll
    for (int dg = 0; dg < 4; ++dg)
      O[row * DIMD + hb + dg * 16 + l15] = f2bf(oa[dg][r] * inv);
  }
}

extern "C" void kernel_launch(void* const* d_in, const int* in_sizes, int n_in,
                              void* d_out, int out_size, void* d_ws, size_t ws_size,
                              hipStream_t stream) {
  const float* x   = (const float*)d_in[0];
  const float* ex  = (const float*)d_in[1];
  const float* Wq  = (const float*)d_in[2];  const float* bq  = (const float*)d_in[3];
  const float* Wk  = (const float*)d_in[4];  const float* bk  = (const float*)d_in[5];
  const float* Wv  = (const float*)d_in[6];  const float* bv  = (const float*)d_in[7];
  const float* Waq = (const float*)d_in[8];  const float* baq = (const float*)d_in[9];
  const float* Wak = (const float*)d_in[10]; const float* bak = (const float*)d_in[11];
  const float* Wav = (const float*)d_in[12]; const float* bav = (const float*)d_in[13];
  const float* Wo  = (const float*)d_in[14]; const float* bo  = (const float*)d_in[15];
  const float* Wao = (const float*)d_in[16]; const float* bao = (const float*)d_in[17];
  const float* gq  = (const float*)d_in[18]; const float* gk  = (const float*)d_in[19];
  const float* gaq = (const float*)d_in[20]; const float* gak = (const float*)d_in[21];
  float* out = (float*)d_out;

  u16* ws = (u16*)d_ws;
  const size_t WSZ = (size_t)DIMD * DIMD;
  u16* xb   = ws;
  u16* exb  = xb + (size_t)NS * DIMD;
  u16* wb   = exb + (size_t)NT * DIMD;
  u16* qcat = wb + 8 * WSZ;
  u16* kcat = qcat + (size_t)LTOT * DIMD;
  u16* vcat = kcat + (size_t)LTOT * DIMD;
  u16* VT   = vcat + (size_t)LTOT * DIMD;
  u16* aout = VT + (size_t)LTOT * DIMD;

  CvtArgs ca;
  const float* srcs[10] = {x, ex, Wq, Wk, Wv, Waq, Wak, Wav, Wo, Wao};
  u16* dsts[10] = {xb, exb, wb, wb + WSZ, wb + 2 * WSZ, wb + 3 * WSZ,
                   wb + 4 * WSZ, wb + 5 * WSZ, wb + 6 * WSZ, wb + 7 * WSZ};
  const int ns[10] = {NS * DIMD, NT * DIMD, (int)WSZ, (int)WSZ, (int)WSZ,
                      (int)WSZ, (int)WSZ, (int)WSZ, (int)WSZ, (int)WSZ};
  for (int i = 0; i < 10; ++i) { ca.src[i] = srcs[i]; ca.dst[i] = dsts[i]; ca.n[i] = ns[i]; }
  cvt_all<<<dim3((NS * DIMD) / 1024, 10), 256, 0, stream>>>(ca);

  QkvArgs qa;
  qa.xb = xb; qa.exb = exb;
  qa.w[0] = wb; qa.w[1] = wb + WSZ; qa.w[2] = wb + 2 * WSZ;
  qa.w[3] = wb + 3 * WSZ; qa.w[4] = wb + 4 * WSZ; qa.w[5] = wb + 5 * WSZ;
  qa.b[0] = bq; qa.b[1] = bk; qa.b[2] = bv;
  qa.b[3] = baq; qa.b[4] = bak; qa.b[5] = bav;
  qa.g[0] = gq; qa.g[1] = gk; qa.g[2] = gaq; qa.g[3] = gak;
  qa.qcat = qcat; qa.kcat = kcat; qa.vcat = vcat;
  qkv_gemm<<<dim3(20, 36), 256, 0, stream>>>(qa);

  vtrans<<<dim3(LTOT / 64, 24), 256, 0, stream>>>(vcat, VT);

  flash_attn<<<dim3(LTOT / 64, 24), 256, 0, stream>>>(qcat, kcat, VT, aout);

  OutArgs oa;
  oa.aout = aout;
  oa.w[0] = wb + 6 * WSZ; oa.w[1] = wb + 7 * WSZ;
  oa.b[0] = bo; oa.b[1] = bao;
  oa.out = out;
  out_gemm<<<dim3(20, 12), 256, 0, stream>>>(oa);
}

// Round 6
// 356.707 us; speedup vs baseline: 1.9565x; 1.0331x over previous
//
#include <hip/hip_runtime.h>

#define DIMD 1536
#define LTOT 2560
#define NS 2048
#define NT 512

typedef __bf16 bf16x8 __attribute__((ext_vector_type(8)));
typedef float f32x4 __attribute__((ext_vector_type(4)));
typedef int i32x2 __attribute__((ext_vector_type(2)));
typedef unsigned short u16;
typedef unsigned int u32;

__device__ __forceinline__ u16 f2bf(float f) {
  union { float f; unsigned u; } v; v.f = f;
  return (u16)((v.u + 0x7fffu + ((v.u >> 16) & 1u)) >> 16);
}

__device__ __forceinline__ u32 cvt_pk_bf16(float a, float b) {
  u32 r;
  asm("v_cvt_pk_bf16_f32 %0, %1, %2" : "=v"(r) : "v"(a), "v"(b));
  return r;
}

__device__ __forceinline__ void gload_lds16(const void* g, void* l) {
  __builtin_amdgcn_global_load_lds(
      (__attribute__((address_space(1))) void*)(g),
      (__attribute__((address_space(3))) void*)(l), 16, 0, 0);
}

struct CvtArgs {
  const float* src[10];
  u16* dst[10];
  int n[10];
};

__global__ __launch_bounds__(256) void cvt_all(CvtArgs a) {
  const int seg = blockIdx.y;
  const int n = a.n[seg];
  const float* s = a.src[seg];
  u16* d = a.dst[seg];
  const int i = (blockIdx.x * 256 + threadIdx.x) * 4;
  if (i < n) {
    float4 v = *reinterpret_cast<const float4*>(s + i);
    ushort4 o;
    o.x = f2bf(v.x); o.y = f2bf(v.y); o.z = f2bf(v.z); o.w = f2bf(v.w);
    *reinterpret_cast<ushort4*>(d + i) = o;
  }
}

// ---------- GEMM: double-buffered BK=32 with counted vmcnt ----------

__device__ __forceinline__ void gemm_stage(const u16* pA, const u16* pW,
                                           u16* As, u16* Bs, int wo) {
#pragma unroll
  for (int p = 0; p < 2; ++p) {
    gload_lds16(pA + (long)p * 64 * DIMD, As + p * 2048 + wo);
    gload_lds16(pW + (long)p * 64 * DIMD, Bs + p * 2048 + wo);
  }
}

__device__ __forceinline__ void gemm_compute(
    const u16* As, const u16* Bs, f32x4 (&acc)[4][4],
    int wr, int wc, int l15, int lh) {
  bf16x8 af[4], bfr[4];
#pragma unroll
  for (int m = 0; m < 4; ++m)
    af[m] = *reinterpret_cast<const bf16x8*>(As + (wr + m * 16 + l15) * 32 + lh * 8);
#pragma unroll
  for (int n = 0; n < 4; ++n)
    bfr[n] = *reinterpret_cast<const bf16x8*>(Bs + (wc + n * 16 + l15) * 32 + lh * 8);
#pragma unroll
  for (int m = 0; m < 4; ++m)
#pragma unroll
    for (int n = 0; n < 4; ++n)
      acc[m][n] = __builtin_amdgcn_mfma_f32_16x16x32_bf16(af[m], bfr[n], acc[m][n], 0, 0, 0);
}

__device__ __forceinline__ void gemm_mainloop(
    const u16* __restrict__ A, const u16* __restrict__ W,
    u16* As0, u16* Bs0, u16* As1, u16* Bs1, f32x4 (&acc)[4][4],
    int w, int lane, int wr, int wc, int l15, int lh) {
  const int base = w * 64 + lane;
  const u16* pA = A + (long)(base >> 2) * DIMD + (base & 3) * 8;
  const u16* pW = W + (long)(base >> 2) * DIMD + (base & 3) * 8;
  const int wo = w * 512;

  gemm_stage(pA, pW, As0, Bs0, wo); pA += 32; pW += 32;
  for (int k0 = 0; k0 < DIMD; k0 += 64) {
    gemm_stage(pA, pW, As1, Bs1, wo); pA += 32; pW += 32;
    asm volatile("s_waitcnt vmcnt(4)" ::: "memory");
    __builtin_amdgcn_s_barrier();
    gemm_compute(As0, Bs0, acc, wr, wc, l15, lh);
    __builtin_amdgcn_s_barrier();
    if (k0 + 64 < DIMD) {
      gemm_stage(pA, pW, As0, Bs0, wo); pA += 32; pW += 32;
      asm volatile("s_waitcnt vmcnt(4)" ::: "memory");
    } else {
      asm volatile("s_waitcnt vmcnt(0)" ::: "memory");
    }
    __builtin_amdgcn_s_barrier();
    gemm_compute(As1, Bs1, acc, wr, wc, l15, lh);
    __builtin_amdgcn_s_barrier();
  }
}

struct QkvArgs {
  const u16* xb; const u16* exb;
  const u16* w[6];
  const float* b[6];
  const float* g[4];
  u16* qcat; u16* kcat; u16* vcat;
};

// grid (20, 36): bx<16 -> x-side (M=2048), bx>=16 -> encoder (M=512).
// by/12 = sel: 0=Q (LN, scale log2e/8 folded), 1=K (LN, swizzled store), 2=V.
__global__ __launch_bounds__(256) void qkv_gemm(QkvArgs a) {
  __shared__ u16 As0[128 * 32];
  __shared__ u16 Bs0[128 * 32];
  __shared__ u16 As1[128 * 32];
  __shared__ u16 Bs1[128 * 32];
  const int tid = threadIdx.x, lane = tid & 63, w = tid >> 6;
  const int l15 = lane & 15, lh = lane >> 4;
  const int side = (blockIdx.x >= 16);
  const int mb = side ? (blockIdx.x - 16) : blockIdx.x;
  const int sel = blockIdx.y / 12;
  const int n0 = (blockIdx.y % 12) * 128;
  const long m0 = (long)mb * 128;
  const long Lbase = side ? NS : 0;
  const int wr = (w >> 1) * 64, wc = (w & 1) * 64;
  const u16* A = (side ? a.exb : a.xb) + m0 * DIMD;
  const u16* W = a.w[side * 3 + sel] + (long)n0 * DIMD;
  const float* bias = a.b[side * 3 + sel];

  f32x4 acc[4][4] = {};
  gemm_mainloop(A, W, As0, Bs0, As1, Bs1, acc, w, lane, wr, wc, l15, lh);

  if (sel == 2) {
    u16* out = a.vcat;
#pragma unroll
    for (int m = 0; m < 4; ++m)
#pragma unroll
      for (int r = 0; r < 4; ++r) {
        const long row = Lbase + m0 + wr + m * 16 + lh * 4 + r;
#pragma unroll
        for (int n = 0; n < 4; ++n)
          out[row * DIMD + n0 + wc + n * 16 + l15] =
              f2bf(acc[m][n][r] + bias[n0 + wc + n * 16 + l15]);
      }
  } else {
    const float* gamma = a.g[side * 2 + sel];
    // Q: fold softmax scale 1/8 AND log2(e) so attention uses bare exp2.
    const float gscale = (sel == 0) ? 0.125f * 1.4426950408889634f : 1.0f;
    u16* out = (sel == 0) ? a.qcat : a.kcat;
    const int swz = (sel == 1);
#pragma unroll
    for (int m = 0; m < 4; ++m) {
      float val[4][4];
#pragma unroll
      for (int n = 0; n < 4; ++n) {
        const float b = bias[n0 + wc + n * 16 + l15];
#pragma unroll
        for (int r = 0; r < 4; ++r) val[n][r] = acc[m][n][r] + b;
      }
      float s1[4], s2[4];
#pragma unroll
      for (int r = 0; r < 4; ++r) {
        s1[r] = 0.f; s2[r] = 0.f;
#pragma unroll
        for (int n = 0; n < 4; ++n) { s1[r] += val[n][r]; s2[r] += val[n][r] * val[n][r]; }
      }
#pragma unroll
      for (int off = 1; off < 16; off <<= 1) {
#pragma unroll
        for (int r = 0; r < 4; ++r) {
          s1[r] += __shfl_xor(s1[r], off, 16);
          s2[r] += __shfl_xor(s2[r], off, 16);
        }
      }
#pragma unroll
      for (int r = 0; r < 4; ++r) {
        const float mu = s1[r] * (1.0f / 64.0f);
        const float var = s2[r] * (1.0f / 64.0f) - mu * mu;
        const float rstd = rsqrtf(var + 1e-5f);
        const long row = Lbase + m0 + wr + m * 16 + lh * 4 + r;
        const int r7s = ((lh * 4 + r) & 7) << 3;
#pragma unroll
        for (int n = 0; n < 4; ++n) {
          const float g = gamma[n * 16 + l15] * gscale;
          const int colg = n0 + wc + n * 16 + l15;
          const int colstore = swz ? ((colg & ~63) | ((colg & 63) ^ r7s)) : colg;
          out[row * DIMD + colstore] = f2bf((val[n][r] - mu) * rstd * g);
        }
      }
    }
  }
}

struct OutArgs {
  const u16* aout;
  const u16* w[2];
  const float* b[2];
  float* out;
};

// grid (20, 12): bx<16 -> img (Wo), bx>=16 -> txt (Wao)
__global__ __launch_bounds__(256) void out_gemm(OutArgs a) {
  __shared__ u16 As0[128 * 32];
  __shared__ u16 Bs0[128 * 32];
  __shared__ u16 As1[128 * 32];
  __shared__ u16 Bs1[128 * 32];
  const int tid = threadIdx.x, lane = tid & 63, w = tid >> 6;
  const int l15 = lane & 15, lh = lane >> 4;
  const int side = (blockIdx.x >= 16);
  const int mb = side ? (blockIdx.x - 16) : blockIdx.x;
  const int n0 = blockIdx.y * 128;
  const long m0 = (long)mb * 128;
  const long Lbase = side ? NS : 0;
  const int wr = (w >> 1) * 64, wc = (w & 1) * 64;
  const u16* A = a.aout + (Lbase + m0) * DIMD;
  const u16* W = a.w[side] + (long)n0 * DIMD;
  const float* bias = a.b[side];

  f32x4 acc[4][4] = {};
  gemm_mainloop(A, W, As0, Bs0, As1, Bs1, acc, w, lane, wr, wc, l15, lh);

#pragma unroll
  for (int m = 0; m < 4; ++m)
#pragma unroll
    for (int r = 0; r < 4; ++r) {
      const long row = Lbase + m0 + wr + m * 16 + lh * 4 + r;
#pragma unroll
      for (int n = 0; n < 4; ++n)
        a.out[row * DIMD + n0 + wc + n * 16 + l15] =
            acc[m][n][r] + bias[n0 + wc + n * 16 + l15];
    }
}

// vcat [L][1536] -> VT [24][64][LTOT], store-swizzled: VT[h][d][k ^ ((d&7)<<3)]
__global__ __launch_bounds__(256) void vtrans(const u16* __restrict__ vcat,
                                              u16* __restrict__ VT) {
  const int tid = threadIdx.x;
  const int kv0 = blockIdx.x * 64;
  const int head = blockIdx.y;
  const long hb = (long)head * 64;
#pragma unroll
  for (int p = 0; p < 2; ++p) {
    const int idx = p * 256 + tid;
    const int kl = idx >> 3, db = (idx & 7) * 8;
    uint4 vv = *reinterpret_cast<const uint4*>(vcat + (long)(kv0 + kl) * DIMD + hb + db);
    const u16* vs = reinterpret_cast<const u16*>(&vv);
#pragma unroll
    for (int i = 0; i < 8; ++i) {
      const int d = db + i;
      VT[(hb + d) * LTOT + ((kv0 + kl) ^ ((d & 7) << 3))] = vs[i];
    }
  }
}

// ---------- Flash attention ----------
// Max-free softmax, swapped QK^T, in-register P fragments, rowsum via
// MFMA-with-ones, double-buffered K/V staging with counted vmcnt.
// grid (LTOT/64, 24), 4 waves, KV tile 128.

__device__ __forceinline__ void attn_stage(const u16* pK, const u16* pV,
                                           u16* Ks, u16* Vs, int wo) {
#pragma unroll
  for (int ph = 0; ph < 4; ++ph) {
    gload_lds16(pK + (long)ph * 32 * DIMD, Ks + ph * 2048 + wo);
    gload_lds16(pV + (long)ph * 16 * LTOT, Vs + ph * 2048 + wo);
  }
}

__device__ __forceinline__ void attn_tile(
    const u16* Ks, const u16* Vs, const bf16x8 (&aq)[2], bf16x8 ones,
    f32x4 (&oa)[4], f32x4& rs, int l15, int lh, int swl, bool bsel) {
  // S^T tile: s[c][r] = S[k = 16c + 4lh + r][q = l15]
  f32x4 s[8] = {};
#pragma unroll
  for (int c = 0; c < 8; ++c)
#pragma unroll
    for (int kh = 0; kh < 2; ++kh) {
      bf16x8 kb = *reinterpret_cast<const bf16x8*>(
          Ks + (c * 16 + l15) * 64 + ((kh * 32 + lh * 8) ^ swl));
      s[c] = __builtin_amdgcn_mfma_f32_16x16x32_bf16(kb, aq[kh], s[c], 0, 0, 0);
    }

  u32 lo[8], hi[8];
#pragma unroll
  for (int c = 0; c < 8; ++c) {
    lo[c] = cvt_pk_bf16(exp2f(s[c][0]), exp2f(s[c][1]));
    hi[c] = cvt_pk_bf16(exp2f(s[c][2]), exp2f(s[c][3]));
  }

#pragma unroll
  for (int ks = 0; ks < 4; ++ks) {
    i32x2 L = __builtin_amdgcn_permlane32_swap((int)lo[2 * ks], (int)lo[2 * ks + 1], false, false);
    i32x2 H = __builtin_amdgcn_permlane32_swap((int)hi[2 * ks], (int)hi[2 * ks + 1], false, false);
    const int sLy = __shfl_xor(L.y, 16);
    const int sHy = __shfl_xor(H.y, 16);
    const int sLx = __shfl_xor(L.x, 16);
    const int sHx = __shfl_xor(H.x, 16);
    union { int w4[4]; bf16x8 v; } pu;
    pu.w4[0] = bsel ? sLy : L.x;
    pu.w4[1] = bsel ? sHy : H.x;
    pu.w4[2] = bsel ? L.y : sLx;
    pu.w4[3] = bsel ? H.y : sHx;
#pragma unroll
    for (int dg = 0; dg < 4; ++dg) {
      bf16x8 vb = *reinterpret_cast<const bf16x8*>(
          Vs + (dg * 16 + l15) * 128 + ((ks * 32 + lh * 8) ^ swl));
      oa[dg] = __builtin_amdgcn_mfma_f32_16x16x32_bf16(pu.v, vb, oa[dg], 0, 0, 0);
    }
    rs = __builtin_amdgcn_mfma_f32_16x16x32_bf16(pu.v, ones, rs, 0, 0, 0);
  }
}

__global__ __launch_bounds__(256) void flash_attn(
    const u16* __restrict__ Q, const u16* __restrict__ K,
    const u16* __restrict__ VT, u16* __restrict__ O) {
  __shared__ u16 Ks0[128 * 64];
  __shared__ u16 Vs0[64 * 128];
  __shared__ u16 Ks1[128 * 64];
  __shared__ u16 Vs1[64 * 128];
  const int tid = threadIdx.x, lane = tid & 63, w = tid >> 6;
  const int l15 = lane & 15, lh = lane >> 4;
  const bool bsel = lh & 1;
  const long hb = (long)blockIdx.y * 64;
  const long q0 = (long)blockIdx.x * 64 + w * 16;
  const int swl = (l15 & 7) << 3;

  bf16x8 aq[2];
#pragma unroll
  for (int kh = 0; kh < 2; ++kh)
    aq[kh] = *reinterpret_cast<const bf16x8*>(Q + (q0 + l15) * DIMD + hb + kh * 32 + lh * 8);

  union { u32 u[4]; bf16x8 v; } onesu;
#pragma unroll
  for (int i = 0; i < 4; ++i) onesu.u[i] = 0x3F803F80u;

  f32x4 oa[4] = {};
  f32x4 rs = {};

  const u16* pK = K + (long)(tid >> 3) * DIMD + hb + (tid & 7) * 8;
  const u16* pV = VT + (hb + (tid >> 4)) * LTOT + (tid & 15) * 8;
  const int wo = w * 512;

  attn_stage(pK, pV, Ks0, Vs0, wo); pK += (long)128 * DIMD; pV += 128;
  for (int kv0 = 0; kv0 < LTOT; kv0 += 256) {
    attn_stage(pK, pV, Ks1, Vs1, wo); pK += (long)128 * DIMD; pV += 128;
    asm volatile("s_waitcnt vmcnt(8)" ::: "memory");
    __builtin_amdgcn_s_barrier();
    attn_tile(Ks0, Vs0, aq, onesu.v, oa, rs, l15, lh, swl, bsel);
    __builtin_amdgcn_s_barrier();
    if (kv0 + 256 < LTOT) {
      attn_stage(pK, pV, Ks0, Vs0, wo); pK += (long)128 * DIMD; pV += 128;
      asm volatile("s_waitcnt vmcnt(8)" ::: "memory");
    } else {
      asm volatile("s_waitcnt vmcnt(0)" ::: "memory");
    }
    __builtin_amdgcn_s_barrier();
    attn_tile(Ks1, Vs1, aq, onesu.v, oa, rs, l15, lh, swl, bsel);
    __builtin_amdgcn_s_barrier();
  }

#pragma unroll
  for (int r = 0; r < 4; ++r) {
    const float inv = 1.0f / rs[r];
    const long row = q0 + lh * 4 + r;
#pragma unroll
    for (int dg = 0; dg < 4; ++dg)
      O[row * DIMD + hb + dg * 16 + l15] = f2bf(oa[dg][r] * inv);
  }
}

extern "C" void kernel_launch(void* const* d_in, const int* in_sizes, int n_in,
                              void* d_out, int out_size, void* d_ws, size_t ws_size,
                              hipStream_t stream) {
  const float* x   = (const float*)d_in[0];
  const float* ex  = (const float*)d_in[1];
  const float* Wq  = (const float*)d_in[2];  const float* bq  = (const float*)d_in[3];
  const float* Wk  = (const float*)d_in[4];  const float* bk  = (const float*)d_in[5];
  const float* Wv  = (const float*)d_in[6];  const float* bv  = (const float*)d_in[7];
  const float* Waq = (const float*)d_in[8];  const float* baq = (const float*)d_in[9];
  const float* Wak = (const float*)d_in[10]; const float* bak = (const float*)d_in[11];
  const float* Wav = (const float*)d_in[12]; const float* bav = (const float*)d_in[13];
  const float* Wo  = (const float*)d_in[14]; const float* bo  = (const float*)d_in[15];
  const float* Wao = (const float*)d_in[16]; const float* bao = (const float*)d_in[17];
  const float* gq  = (const float*)d_in[18]; const float* gk  = (const float*)d_in[19];
  const float* gaq = (const float*)d_in[20]; const float* gak = (const float*)d_in[21];
  float* out = (float*)d_out;

  u16* ws = (u16*)d_ws;
  const size_t WSZ = (size_t)DIMD * DIMD;
  u16* xb   = ws;
  u16* exb  = xb + (size_t)NS * DIMD;
  u16* wb   = exb + (size_t)NT * DIMD;
  u16* qcat = wb + 8 * WSZ;
  u16* kcat = qcat + (size_t)LTOT * DIMD;
  u16* vcat = kcat + (size_t)LTOT * DIMD;
  u16* VT   = vcat + (size_t)LTOT * DIMD;
  u16* aout = VT + (size_t)LTOT * DIMD;

  CvtArgs ca;
  const float* srcs[10] = {x, ex, Wq, Wk, Wv, Waq, Wak, Wav, Wo, Wao};
  u16* dsts[10] = {xb, exb, wb, wb + WSZ, wb + 2 * WSZ, wb + 3 * WSZ,
                   wb + 4 * WSZ, wb + 5 * WSZ, wb + 6 * WSZ, wb + 7 * WSZ};
  const int ns[10] = {NS * DIMD, NT * DIMD, (int)WSZ, (int)WSZ, (int)WSZ,
                      (int)WSZ, (int)WSZ, (int)WSZ, (int)WSZ, (int)WSZ};
  for (int i = 0; i < 10; ++i) { ca.src[i] = srcs[i]; ca.dst[i] = dsts[i]; ca.n[i] = ns[i]; }
  cvt_all<<<dim3((NS * DIMD) / 1024, 10), 256, 0, stream>>>(ca);

  QkvArgs qa;
  qa.xb = xb; qa.exb = exb;
  qa.w[0] = wb; qa.w[1] = wb + WSZ; qa.w[2] = wb + 2 * WSZ;
  qa.w[3] = wb + 3 * WSZ; qa.w[4] = wb + 4 * WSZ; qa.w[5] = wb + 5 * WSZ;
  qa.b[0] = bq; qa.b[1] = bk; qa.b[2] = bv;
  qa.b[3] = baq; qa.b[4] = bak; qa.b[5] = bav;
  qa.g[0] = gq; qa.g[1] = gk; qa.g[2] = gaq; qa.g[3] = gak;
  qa.qcat = qcat; qa.kcat = kcat; qa.vcat = vcat;
  qkv_gemm<<<dim3(20, 36), 256, 0, stream>>>(qa);

  vtrans<<<dim3(LTOT / 64, 24), 256, 0, stream>>>(vcat, VT);

  flash_attn<<<dim3(LTOT / 64, 24), 256, 0, stream>>>(qcat, kcat, VT, aout);

  OutArgs oa;
  oa.aout = aout;
  oa.w[0] = wb + 6 * WSZ; oa.w[1] = wb + 7 * WSZ;
  oa.b[0] = bo; oa.b[1] = bao;
  oa.out = out;
  out_gemm<<<dim3(20, 12), 256, 0, stream>>>(oa);
}

// Round 7
// 316.538 us; speedup vs baseline: 2.2048x; 1.1269x over previous
//
#include <hip/hip_runtime.h>

#define DIMD 1536
#define LTOT 2560
#define NS 2048
#define NT 512

typedef __bf16 bf16x8 __attribute__((ext_vector_type(8)));
typedef float f32x4 __attribute__((ext_vector_type(4)));
typedef int i32x2 __attribute__((ext_vector_type(2)));
typedef unsigned short u16;
typedef unsigned int u32;

#if __has_builtin(__builtin_amdgcn_exp2f)
#define EXP2(x) __builtin_amdgcn_exp2f(x)
#else
#define EXP2(x) exp2f(x)
#endif

__device__ __forceinline__ u16 f2bf(float f) {
  union { float f; unsigned u; } v; v.f = f;
  return (u16)((v.u + 0x7fffu + ((v.u >> 16) & 1u)) >> 16);
}

__device__ __forceinline__ u32 cvt_pk_bf16(float a, float b) {
  u32 r;
  asm("v_cvt_pk_bf16_f32 %0, %1, %2" : "=v"(r) : "v"(a), "v"(b));
  return r;
}

__device__ __forceinline__ void gload_lds16(const void* g, void* l) {
  __builtin_amdgcn_global_load_lds(
      (__attribute__((address_space(1))) void*)(g),
      (__attribute__((address_space(3))) void*)(l), 16, 0, 0);
}

struct CvtArgs {
  const float* src[10];
  u16* dst[10];
  int n[10];
};

__global__ __launch_bounds__(256) void cvt_all(CvtArgs a) {
  const int seg = blockIdx.y;
  const int n = a.n[seg];
  const float* s = a.src[seg];
  u16* d = a.dst[seg];
  const int i = (blockIdx.x * 256 + threadIdx.x) * 4;
  if (i < n) {
    float4 v = *reinterpret_cast<const float4*>(s + i);
    ushort4 o;
    o.x = f2bf(v.x); o.y = f2bf(v.y); o.z = f2bf(v.z); o.w = f2bf(v.w);
    *reinterpret_cast<ushort4*>(d + i) = o;
  }
}

// ---------- GEMM: 3-buffer BK=32, 2-ahead prefetch, counted vmcnt ----------

__device__ __forceinline__ void gemm_stage(const u16* pA, const u16* pW,
                                           u16* As, u16* Bs, int wo) {
  gload_lds16(pA, As + wo);
  gload_lds16(pA + (long)64 * DIMD, As + 2048 + wo);
  gload_lds16(pW, Bs + wo);
  gload_lds16(pW + (long)64 * DIMD, Bs + 2048 + wo);
}

__device__ __forceinline__ void gemm_compute(
    const u16* As, const u16* Bs, f32x4 (&acc)[4][4],
    int wr, int wc, int l15, int lh) {
  bf16x8 af[4], bfr[4];
#pragma unroll
  for (int m = 0; m < 4; ++m)
    af[m] = *reinterpret_cast<const bf16x8*>(As + (wr + m * 16 + l15) * 32 + lh * 8);
#pragma unroll
  for (int n = 0; n < 4; ++n)
    bfr[n] = *reinterpret_cast<const bf16x8*>(Bs + (wc + n * 16 + l15) * 32 + lh * 8);
#pragma unroll
  for (int m = 0; m < 4; ++m)
#pragma unroll
    for (int n = 0; n < 4; ++n)
      acc[m][n] = __builtin_amdgcn_mfma_f32_16x16x32_bf16(af[m], bfr[n], acc[m][n], 0, 0, 0);
}

#define VMW(N) asm volatile("s_waitcnt vmcnt(" #N ")" ::: "memory")
#define BAR() __builtin_amdgcn_s_barrier()

// K = 1536 = 48 steps of 32. 3 buffers, 2 stages in flight.
__device__ __forceinline__ void gemm_mainloop(
    const u16* __restrict__ A, const u16* __restrict__ W,
    u16* As0, u16* Bs0, u16* As1, u16* Bs1, u16* As2, u16* Bs2,
    f32x4 (&acc)[4][4], int w, int lane, int wr, int wc, int l15, int lh) {
  const int tid = w * 64 + lane;
  const u16* pA = A + (long)(tid >> 2) * DIMD + (tid & 3) * 8;
  const u16* pW = W + (long)(tid >> 2) * DIMD + (tid & 3) * 8;
  const int wo = w * 512;

  gemm_stage(pA, pW, As0, Bs0, wo); pA += 32; pW += 32;
  gemm_stage(pA, pW, As1, Bs1, wo); pA += 32; pW += 32;
  for (int i = 0; i < 15; ++i) {
    gemm_stage(pA, pW, As2, Bs2, wo); pA += 32; pW += 32;
    VMW(8); BAR();
    gemm_compute(As0, Bs0, acc, wr, wc, l15, lh);
    BAR();
    gemm_stage(pA, pW, As0, Bs0, wo); pA += 32; pW += 32;
    VMW(8); BAR();
    gemm_compute(As1, Bs1, acc, wr, wc, l15, lh);
    BAR();
    gemm_stage(pA, pW, As1, Bs1, wo); pA += 32; pW += 32;
    VMW(8); BAR();
    gemm_compute(As2, Bs2, acc, wr, wc, l15, lh);
    BAR();
  }
  // k = 45,46,47 -> bufs 0,1,2 ; stage 47 -> buf2
  gemm_stage(pA, pW, As2, Bs2, wo);
  VMW(8); BAR();
  gemm_compute(As0, Bs0, acc, wr, wc, l15, lh);
  BAR();
  VMW(4); BAR();
  gemm_compute(As1, Bs1, acc, wr, wc, l15, lh);
  BAR();
  VMW(0); BAR();
  gemm_compute(As2, Bs2, acc, wr, wc, l15, lh);
}

struct QkvArgs {
  const u16* xb; const u16* exb;
  const u16* w[6];
  const float* b[6];
  const float* g[4];
  u16* qcat; u16* kcat; u16* VT;
};

// grid (20, 36): bx<16 -> x-side (M=2048), bx>=16 -> encoder (M=512).
// by/12 = sel: 0=Q (LN, log2e/8 folded), 1=K (LN, swizzled), 2=V (-> VT direct).
__global__ __launch_bounds__(256) void qkv_gemm(QkvArgs a) {
  __shared__ u16 As0[128 * 32];
  __shared__ u16 Bs0[128 * 32];
  __shared__ u16 As1[128 * 32];
  __shared__ u16 Bs1[128 * 32];
  __shared__ u16 As2[128 * 32];
  __shared__ u16 Bs2[128 * 32];
  const int tid = threadIdx.x, lane = tid & 63, w = tid >> 6;
  const int l15 = lane & 15, lh = lane >> 4;
  const int side = (blockIdx.x >= 16);
  const int mb = side ? (blockIdx.x - 16) : blockIdx.x;
  const int sel = blockIdx.y / 12;
  const int n0 = (blockIdx.y % 12) * 128;
  const long m0 = (long)mb * 128;
  const long Lbase = side ? NS : 0;
  const int wr = (w >> 1) * 64, wc = (w & 1) * 64;
  const u16* A = (side ? a.exb : a.xb) + m0 * DIMD;
  const u16* W = a.w[side * 3 + sel] + (long)n0 * DIMD;
  const float* bias = a.b[side * 3 + sel];

  f32x4 acc[4][4] = {};
  gemm_mainloop(A, W, As0, Bs0, As1, Bs1, As2, Bs2, acc, w, lane, wr, wc, l15, lh);

  if (sel == 2) {
    // V: write transposed+swizzled VT[h][d][L ^ ((d&7)<<3)] directly.
    u16* VT = a.VT;
#pragma unroll
    for (int m = 0; m < 4; ++m)
#pragma unroll
      for (int r = 0; r < 4; ++r) {
        const int row = (int)(Lbase + m0) + wr + m * 16 + lh * 4 + r;
#pragma unroll
        for (int n = 0; n < 4; ++n) {
          const int col = n0 + wc + n * 16 + l15;
          const float v = acc[m][n][r] + bias[col];
          VT[(long)col * LTOT + (row ^ ((col & 7) << 3))] = f2bf(v);
        }
      }
  } else {
    const float* gamma = a.g[side * 2 + sel];
    // Q: fold softmax scale 1/8 AND log2(e) so attention uses bare exp2.
    const float gscale = (sel == 0) ? 0.125f * 1.4426950408889634f : 1.0f;
    u16* out = (sel == 0) ? a.qcat : a.kcat;
    const int swz = (sel == 1);
#pragma unroll
    for (int m = 0; m < 4; ++m) {
      float val[4][4];
#pragma unroll
      for (int n = 0; n < 4; ++n) {
        const float b = bias[n0 + wc + n * 16 + l15];
#pragma unroll
        for (int r = 0; r < 4; ++r) val[n][r] = acc[m][n][r] + b;
      }
      float s1[4], s2[4];
#pragma unroll
      for (int r = 0; r < 4; ++r) {
        s1[r] = 0.f; s2[r] = 0.f;
#pragma unroll
        for (int n = 0; n < 4; ++n) { s1[r] += val[n][r]; s2[r] += val[n][r] * val[n][r]; }
      }
#pragma unroll
      for (int off = 1; off < 16; off <<= 1) {
#pragma unroll
        for (int r = 0; r < 4; ++r) {
          s1[r] += __shfl_xor(s1[r], off, 16);
          s2[r] += __shfl_xor(s2[r], off, 16);
        }
      }
#pragma unroll
      for (int r = 0; r < 4; ++r) {
        const float mu = s1[r] * (1.0f / 64.0f);
        const float var = s2[r] * (1.0f / 64.0f) - mu * mu;
        const float rstd = rsqrtf(var + 1e-5f);
        const long row = Lbase + m0 + wr + m * 16 + lh * 4 + r;
        const int r7s = ((lh * 4 + r) & 7) << 3;
#pragma unroll
        for (int n = 0; n < 4; ++n) {
          const float g = gamma[n * 16 + l15] * gscale;
          const int colg = n0 + wc + n * 16 + l15;
          const int colstore = swz ? ((colg & ~63) | ((colg & 63) ^ r7s)) : colg;
          out[row * DIMD + colstore] = f2bf((val[n][r] - mu) * rstd * g);
        }
      }
    }
  }
}

struct OutArgs {
  const u16* aout;
  const u16* w[2];
  const float* b[2];
  float* out;
};

// grid (20, 12): bx<16 -> img (Wo), bx>=16 -> txt (Wao)
__global__ __launch_bounds__(256) void out_gemm(OutArgs a) {
  __shared__ u16 As0[128 * 32];
  __shared__ u16 Bs0[128 * 32];
  __shared__ u16 As1[128 * 32];
  __shared__ u16 Bs1[128 * 32];
  __shared__ u16 As2[128 * 32];
  __shared__ u16 Bs2[128 * 32];
  const int tid = threadIdx.x, lane = tid & 63, w = tid >> 6;
  const int l15 = lane & 15, lh = lane >> 4;
  const int side = (blockIdx.x >= 16);
  const int mb = side ? (blockIdx.x - 16) : blockIdx.x;
  const int n0 = blockIdx.y * 128;
  const long m0 = (long)mb * 128;
  const long Lbase = side ? NS : 0;
  const int wr = (w >> 1) * 64, wc = (w & 1) * 64;
  const u16* A = a.aout + (Lbase + m0) * DIMD;
  const u16* W = a.w[side] + (long)n0 * DIMD;
  const float* bias = a.b[side];

  f32x4 acc[4][4] = {};
  gemm_mainloop(A, W, As0, Bs0, As1, Bs1, As2, Bs2, acc, w, lane, wr, wc, l15, lh);

#pragma unroll
  for (int m = 0; m < 4; ++m)
#pragma unroll
    for (int r = 0; r < 4; ++r) {
      const long row = Lbase + m0 + wr + m * 16 + lh * 4 + r;
#pragma unroll
      for (int n = 0; n < 4; ++n)
        a.out[row * DIMD + n0 + wc + n * 16 + l15] =
            acc[m][n][r] + bias[n0 + wc + n * 16 + l15];
    }
}

// ---------- Flash attention ----------
// Max-free softmax, swapped QK^T, in-register P via permlane only,
// rowsum via MFMA-with-ones, KVBLK=64 ping-pong with counted vmcnt.
// grid (LTOT/64, 24), 4 waves; wave w owns 16 Q rows.

__device__ __forceinline__ void attn_stage(const u16* pK, const u16* pV,
                                           u16* Ks, u16* Vs, int wo) {
  gload_lds16(pK, Ks + wo);
  gload_lds16(pK + (long)32 * DIMD, Ks + 2048 + wo);
  gload_lds16(pV, Vs + wo);
  gload_lds16(pV + (long)32 * LTOT, Vs + 2048 + wo);
}

__device__ __forceinline__ void attn_tile(
    const u16* Ks, const u16* Vs, const bf16x8 (&aq)[2], bf16x8 ones,
    f32x4 (&oa)[4], f32x4& rs, int l15, int lh, int swl, bool bsel) {
  // S^T tile: s[c][r] = S[k = 16c + 4lh + r][q = l15]
  f32x4 s[4] = {};
#pragma unroll
  for (int c = 0; c < 4; ++c)
#pragma unroll
    for (int kh = 0; kh < 2; ++kh) {
      bf16x8 kb = *reinterpret_cast<const bf16x8*>(
          Ks + (c * 16 + l15) * 64 + ((kh * 32 + lh * 8) ^ swl));
      s[c] = __builtin_amdgcn_mfma_f32_16x16x32_bf16(kb, aq[kh], s[c], 0, 0, 0);
    }

  u32 lo[4], hi[4];
#pragma unroll
  for (int c = 0; c < 4; ++c) {
    lo[c] = cvt_pk_bf16(EXP2(s[c][0]), EXP2(s[c][1]));
    hi[c] = cvt_pk_bf16(EXP2(s[c][2]), EXP2(s[c][3]));
  }

#pragma unroll
  for (int ks = 0; ks < 2; ++ks) {
    i32x2 L = __builtin_amdgcn_permlane32_swap((int)lo[2 * ks], (int)lo[2 * ks + 1], false, false);
    i32x2 H = __builtin_amdgcn_permlane32_swap((int)hi[2 * ks], (int)hi[2 * ks + 1], false, false);
    union { int w4[4]; bf16x8 v; } pu;
#if __has_builtin(__builtin_amdgcn_permlane16_swap)
    i32x2 W02 = __builtin_amdgcn_permlane16_swap(L.x, L.y, false, false);
    i32x2 W13 = __builtin_amdgcn_permlane16_swap(H.x, H.y, false, false);
    pu.w4[0] = W02.x; pu.w4[1] = W13.x; pu.w4[2] = W02.y; pu.w4[3] = W13.y;
#else
    const int sLy = __shfl_xor(L.y, 16);
    const int sHy = __shfl_xor(H.y, 16);
    const int sLx = __shfl_xor(L.x, 16);
    const int sHx = __shfl_xor(H.x, 16);
    pu.w4[0] = bsel ? sLy : L.x;
    pu.w4[1] = bsel ? sHy : H.x;
    pu.w4[2] = bsel ? L.y : sLx;
    pu.w4[3] = bsel ? H.y : sHx;
#endif
#pragma unroll
    for (int dg = 0; dg < 4; ++dg) {
      bf16x8 vb = *reinterpret_cast<const bf16x8*>(
          Vs + (dg * 16 + l15) * 64 + ((ks * 32 + lh * 8) ^ swl));
      oa[dg] = __builtin_amdgcn_mfma_f32_16x16x32_bf16(pu.v, vb, oa[dg], 0, 0, 0);
    }
    rs = __builtin_amdgcn_mfma_f32_16x16x32_bf16(pu.v, ones, rs, 0, 0, 0);
  }
}

__global__ __launch_bounds__(256) void flash_attn(
    const u16* __restrict__ Q, const u16* __restrict__ K,
    const u16* __restrict__ VT, u16* __restrict__ O) {
  __shared__ u16 Ks0[64 * 64];
  __shared__ u16 Vs0[64 * 64];
  __shared__ u16 Ks1[64 * 64];
  __shared__ u16 Vs1[64 * 64];
  const int tid = threadIdx.x, lane = tid & 63, w = tid >> 6;
  const int l15 = lane & 15, lh = lane >> 4;
  const bool bsel = lh & 1;
  const long hb = (long)blockIdx.y * 64;
  const long q0 = (long)blockIdx.x * 64 + w * 16;
  const int swl = (l15 & 7) << 3;

  bf16x8 aq[2];
#pragma unroll
  for (int kh = 0; kh < 2; ++kh)
    aq[kh] = *reinterpret_cast<const bf16x8*>(Q + (q0 + l15) * DIMD + hb + kh * 32 + lh * 8);

  union { u32 u[4]; bf16x8 v; } onesu;
#pragma unroll
  for (int i = 0; i < 4; ++i) onesu.u[i] = 0x3F803F80u;

  f32x4 oa[4] = {};
  f32x4 rs = {};

  const u16* pK = K + (long)(tid >> 3) * DIMD + hb + (tid & 7) * 8;
  const u16* pV = VT + (hb + (tid >> 3)) * LTOT + (tid & 7) * 8;
  const int wo = w * 512;

  attn_stage(pK, pV, Ks0, Vs0, wo);
  pK += (long)64 * DIMD; pV += 64;
  for (int t = 0; t < 40; t += 2) {
    attn_stage(pK, pV, Ks1, Vs1, wo);
    pK += (long)64 * DIMD; pV += 64;
    VMW(4); BAR();
    __builtin_amdgcn_s_setprio(1);
    attn_tile(Ks0, Vs0, aq, onesu.v, oa, rs, l15, lh, swl, bsel);
    __builtin_amdgcn_s_setprio(0);
    BAR();
    if (t + 2 < 40) {
      attn_stage(pK, pV, Ks0, Vs0, wo);
      pK += (long)64 * DIMD; pV += 64;
      VMW(4);
    } else {
      VMW(0);
    }
    BAR();
    __builtin_amdgcn_s_setprio(1);
    attn_tile(Ks1, Vs1, aq, onesu.v, oa, rs, l15, lh, swl, bsel);
    __builtin_amdgcn_s_setprio(0);
    BAR();
  }

#pragma unroll
  for (int r = 0; r < 4; ++r) {
    const float inv = 1.0f / rs[r];
    const long row = q0 + lh * 4 + r;
#pragma unroll
    for (int dg = 0; dg < 4; ++dg)
      O[row * DIMD + hb + dg * 16 + l15] = f2bf(oa[dg][r] * inv);
  }
}

extern "C" void kernel_launch(void* const* d_in, const int* in_sizes, int n_in,
                              void* d_out, int out_size, void* d_ws, size_t ws_size,
                              hipStream_t stream) {
  const float* x   = (const float*)d_in[0];
  const float* ex  = (const float*)d_in[1];
  const float* Wq  = (const float*)d_in[2];  const float* bq  = (const float*)d_in[3];
  const float* Wk  = (const float*)d_in[4];  const float* bk  = (const float*)d_in[5];
  const float* Wv  = (const float*)d_in[6];  const float* bv  = (const float*)d_in[7];
  const float* Waq = (const float*)d_in[8];  const float* baq = (const float*)d_in[9];
  const float* Wak = (const float*)d_in[10]; const float* bak = (const float*)d_in[11];
  const float* Wav = (const float*)d_in[12]; const float* bav = (const float*)d_in[13];
  const float* Wo  = (const float*)d_in[14]; const float* bo  = (const float*)d_in[15];
  const float* Wao = (const float*)d_in[16]; const float* bao = (const float*)d_in[17];
  const float* gq  = (const float*)d_in[18]; const float* gk  = (const float*)d_in[19];
  const float* gaq = (const float*)d_in[20]; const float* gak = (const float*)d_in[21];
  float* out = (float*)d_out;

  u16* ws = (u16*)d_ws;
  const size_t WSZ = (size_t)DIMD * DIMD;
  u16* xb   = ws;
  u16* exb  = xb + (size_t)NS * DIMD;
  u16* wb   = exb + (size_t)NT * DIMD;
  u16* qcat = wb + 8 * WSZ;
  u16* kcat = qcat + (size_t)LTOT * DIMD;
  u16* VT   = kcat + (size_t)LTOT * DIMD;
  u16* aout = VT + (size_t)LTOT * DIMD;

  CvtArgs ca;
  const float* srcs[10] = {x, ex, Wq, Wk, Wv, Waq, Wak, Wav, Wo, Wao};
  u16* dsts[10] = {xb, exb, wb, wb + WSZ, wb + 2 * WSZ, wb + 3 * WSZ,
                   wb + 4 * WSZ, wb + 5 * WSZ, wb + 6 * WSZ, wb + 7 * WSZ};
  const int ns[10] = {NS * DIMD, NT * DIMD, (int)WSZ, (int)WSZ, (int)WSZ,
                      (int)WSZ, (int)WSZ, (int)WSZ, (int)WSZ, (int)WSZ};
  for (int i = 0; i < 10; ++i) { ca.src[i] = srcs[i]; ca.dst[i] = dsts[i]; ca.n[i] = ns[i]; }
  cvt_all<<<dim3((NS * DIMD) / 1024, 10), 256, 0, stream>>>(ca);

  QkvArgs qa;
  qa.xb = xb; qa.exb = exb;
  qa.w[0] = wb; qa.w[1] = wb + WSZ; qa.w[2] = wb + 2 * WSZ;
  qa.w[3] = wb + 3 * WSZ; qa.w[4] = wb + 4 * WSZ; qa.w[5] = wb + 5 * WSZ;
  qa.b[0] = bq; qa.b[1] = bk; qa.b[2] = bv;
  qa.b[3] = baq; qa.b[4] = bak; qa.b[5] = bav;
  qa.g[0] = gq; qa.g[1] = gk; qa.g[2] = gaq; qa.g[3] = gak;
  qa.qcat = qcat; qa.kcat = kcat; qa.VT = VT;
  qkv_gemm<<<dim3(20, 36), 256, 0, stream>>>(qa);

  flash_attn<<<dim3(LTOT / 64, 24), 256, 0, stream>>>(qcat, kcat, VT, aout);

  OutArgs oa;
  oa.aout = aout;
  oa.w[0] = wb + 6 * WSZ; oa.w[1] = wb + 7 * WSZ;
  oa.b[0] = bo; oa.b[1] = bao;
  oa.out = out;
  out_gemm<<<dim3(20, 12), 256, 0, stream>>>(oa);
}